// Round 10
// baseline (1626.362 us; speedup 1.0000x reference)
//
#include <hip/hip_runtime.h>
#include <hip/hip_bf16.h>

#define TT 1024
#define HH 2048
#define EE 16
#define KK 4
#define II 1408
#define IIS 2816
#define GU_MAXT 448
#define DN_MAXT 288

typedef __bf16 bf16x8 __attribute__((ext_vector_type(8)));
typedef float f32x4 __attribute__((ext_vector_type(4)));

__device__ __forceinline__ f32x4 mfma16(bf16x8 a, bf16x8 b, f32x4 c) {
  return __builtin_amdgcn_mfma_f32_16x16x32_bf16(a, b, c, 0, 0, 0);
}

__device__ __forceinline__ void gl_lds16(const void* g, void* l) {
  __builtin_amdgcn_global_load_lds(
      (const __attribute__((address_space(1))) void*)g,
      (__attribute__((address_space(3))) void*)l, 16, 0, 0);
}

__device__ __forceinline__ unsigned int pk2(float a, float b) {
  unsigned short lo = __builtin_bit_cast(unsigned short, (__bf16)a);
  unsigned short hi = __builtin_bit_cast(unsigned short, (__bf16)b);
  return (unsigned int)lo | ((unsigned int)hi << 16);
}

__device__ __forceinline__ float bf2f(unsigned short u) {
  return __builtin_bit_cast(float, (unsigned int)u << 16);
}

// ---------------- routing: logits + noaux_tc top-k ----------------
__global__ __launch_bounds__(256)
void k_route(const float* __restrict__ x, const float* __restrict__ gw,
             const float* __restrict__ gb,
             int* __restrict__ topk_idx, float* __restrict__ wvec,
             __bf16* __restrict__ xb)
{
  const int t = blockIdx.x;
  const int tid = threadIdx.x;
  float a[EE];
#pragma unroll
  for (int e = 0; e < EE; ++e) a[e] = 0.f;
  for (int h = tid; h < HH; h += 256) {
    float xv = x[(size_t)t * HH + h];
    xb[(size_t)t * HH + h] = (__bf16)xv;
#pragma unroll
    for (int e = 0; e < EE; ++e) a[e] += xv * gw[e * HH + h];
  }
  __shared__ float part[4][EE];
  const int lane = tid & 63, wv = tid >> 6;
#pragma unroll
  for (int e = 0; e < EE; ++e) {
    float v = a[e];
#pragma unroll
    for (int off = 32; off > 0; off >>= 1) v += __shfl_xor(v, off);
    if (lane == 0) part[wv][e] = v;
  }
  __syncthreads();
  if (tid == 0) {
    float sc[EE], sb[EE];
    for (int e = 0; e < EE; ++e) {
      float lg = part[0][e] + part[1][e] + part[2][e] + part[3][e];
      sc[e] = 1.f / (1.f + expf(-lg));
      sb[e] = sc[e] + gb[e];
    }
    float gsc[4];
    for (int g = 0; g < 4; ++g) {
      float m1 = -1e30f, m2 = -1e30f;
      for (int j = 0; j < 4; ++j) {
        float v = sb[g * 4 + j];
        if (v > m1) { m2 = m1; m1 = v; } else if (v > m2) { m2 = v; }
      }
      gsc[g] = m1 + m2;
    }
    int g1 = 0; float b1 = gsc[0];
    for (int g = 1; g < 4; ++g) if (gsc[g] > b1) { b1 = gsc[g]; g1 = g; }
    int g2 = 0; float b2 = -1e30f;
    for (int g = 0; g < 4; ++g) if (g != g1 && gsc[g] > b2) { b2 = gsc[g]; g2 = g; }
    bool used[EE];
    for (int e = 0; e < EE; ++e) used[e] = !(((e >> 2) == g1) || ((e >> 2) == g2));
    int sel[KK]; float sw[KK]; float ssum = 0.f;
    for (int j = 0; j < KK; ++j) {
      float best = -1e30f; int bi = 0;
      for (int e = 0; e < EE; ++e)
        if (!used[e] && sb[e] > best) { best = sb[e]; bi = e; }
      used[bi] = true; sel[j] = bi; sw[j] = sc[bi]; ssum += sc[bi];
    }
    float s = 2.5f / (ssum + 1e-20f);
    for (int j = 0; j < KK; ++j) {
      topk_idx[t * KK + j] = sel[j];
      wvec[t * KK + j] = sw[j] * s;
    }
  }
}

// ------ deterministic expert lists + compacted tile tables -------
// gu: BM=256 x BN=128; dn: BM=256 x BN=256
__global__ __launch_bounds__(1024)
void k_lists(const int* __restrict__ topk_idx,
             int* __restrict__ counts, int* __restrict__ offs,
             int* __restrict__ list, int* __restrict__ row_of,
             int* __restrict__ hdr, int* __restrict__ gu_tab,
             int* __restrict__ dn_tab)
{
  const int t = threadIdx.x;
  const int lane = t & 63, wv = t >> 6;
  const int e0 = topk_idx[t * 4 + 0], e1 = topk_idx[t * 4 + 1],
            e2 = topk_idx[t * 4 + 2], e3 = topk_idx[t * 4 + 3];
  __shared__ int wtot[16];
  __shared__ int cnt[EE];
  __shared__ int offsh[EE + 1];
  __shared__ int rtn[EE], gpre[EE + 1], dpre[EE + 1];
  int p0 = 0, p1 = 0, p2 = 0, p3 = 0;
  for (int e = 0; e < EE; ++e) {
    bool f = (e0 == e) || (e1 == e) || (e2 == e) || (e3 == e);
    unsigned long long b = __ballot(f);
    if (lane == 0) wtot[wv] = __popcll(b);
    __syncthreads();
    int wo = 0;
    for (int w2 = 0; w2 < wv; ++w2) wo += wtot[w2];
    if (f) {
      int pos = wo + __popcll(b & ((1ull << lane) - 1ull));
      list[e * TT + pos] = t;
      if (e0 == e) p0 = pos; else if (e1 == e) p1 = pos;
      else if (e2 == e) p2 = pos; else p3 = pos;
    }
    if (t == 0) {
      int tot = 0;
      for (int w2 = 0; w2 < 16; ++w2) tot += wtot[w2];
      cnt[e] = tot;
    }
    __syncthreads();
  }
  if (t == 0) {
    offsh[0] = 0;
    for (int e = 0; e < EE; ++e) offsh[e + 1] = offsh[e] + cnt[e];
    for (int e = 0; e < EE; ++e) { counts[e] = cnt[e]; offs[e] = offsh[e]; }
    gpre[0] = 0; dpre[0] = 0;
    for (int e = 0; e < EE; ++e) {
      int rr = (cnt[e] + 255) >> 8;           // ceil(cnt/256)
      rtn[e] = rr;
      gpre[e + 1] = gpre[e] + rr * (II / 128);
      dpre[e + 1] = dpre[e] + rr * (HH / 256);
    }
    hdr[0] = gpre[EE] + 4 * (IIS / 128);      // shared: 4 row-tiles of 256
    hdr[1] = dpre[EE] + 4 * (HH / 256);
  }
  __syncthreads();
  row_of[t * 4 + 0] = offsh[e0] + p0;
  row_of[t * 4 + 1] = offsh[e1] + p1;
  row_of[t * 4 + 2] = offsh[e2] + p2;
  row_of[t * 4 + 3] = offsh[e3] + p3;
  if (t < EE) {
    int rr = rtn[t];
    int p = gpre[t];
    for (int nt = 0; nt < II / 128; ++nt)
      for (int rt = 0; rt < rr; ++rt) gu_tab[p++] = (t << 16) | (rt << 8) | nt;
    p = dpre[t];
    for (int nt = 0; nt < HH / 256; ++nt)
      for (int rt = 0; rt < rr; ++rt) dn_tab[p++] = (t << 16) | (rt << 8) | nt;
  } else if (t == EE) {
    int p = gpre[EE];
    for (int nt = 0; nt < IIS / 128; ++nt)
      for (int rt = 0; rt < 4; ++rt) gu_tab[p++] = (EE << 16) | (rt << 8) | nt;
    p = dpre[EE];
    for (int nt = 0; nt < HH / 256; ++nt)
      for (int rt = 0; rt < 4; ++rt) dn_tab[p++] = (EE << 16) | (rt << 8) | nt;
  }
}

// ---- gate/up GEMM: BM=256 BN=128 BK=64, direct fp32 B (reg-staged + pack) ----
// A image (gl_lds, pre-swizzled src): slot s -> (r=s>>3, k8=(s&7)^(r&7)).
// B image (ds_write): slot(r,k8) = r*8 + (k8 ^ ((r>>1)&7)) -- transposed write
// conflict-free (8-way swz spread), fragment read 2-way (free).
__global__ __launch_bounds__(512)
void k_gu5(const __bf16* __restrict__ xb,
           const float* __restrict__ wg, const float* __restrict__ wu,
           const float* __restrict__ sg, const float* __restrict__ su,
           const int* __restrict__ counts, const int* __restrict__ offs,
           const int* __restrict__ list, const int* __restrict__ hdr,
           const int* __restrict__ gu_tab,
           __bf16* __restrict__ a_buf, __bf16* __restrict__ s_buf)
{
  const int nwg = hdr[0];
  const int orig = blockIdx.x;
  if (orig >= nwg) return;
  const int qq = nwg >> 3, r8 = nwg & 7, xcd = orig & 7;
  const int wgid = (xcd < r8 ? xcd * (qq + 1) : r8 * (qq + 1) + (xcd - r8) * qq)
                   + (orig >> 3);
  const int ent = gu_tab[wgid];
  const int e = ent >> 16, rt = (ent >> 8) & 255, nt = ent & 255;
  const bool SH = (e == EE);
  const int Nt = SH ? IIS : II;
  const int ldw = Nt;
  const int n0 = nt * 128, row0 = rt * 256;
  const int n_rows = SH ? TT : counts[e];
  if (row0 >= n_rows) return;
  const int base = SH ? 0 : offs[e];
  const float* Bg = SH ? sg : wg + (size_t)e * HH * II;   // [k][n] fp32
  const float* Bu = SH ? su : wu + (size_t)e * HH * II;
  __bf16* outp = SH ? s_buf : a_buf;

  __shared__ uint4 As[2][2048];    // 64KB
  __shared__ uint4 Bgs[2][1024];   // 32KB
  __shared__ uint4 Bus[2][1024];   // 32KB
  __shared__ int toks[256];

  const int tid = threadIdx.x;
  const int lane = tid & 63, w = tid >> 6;
  if (tid < 256) {
    int rr = row0 + tid;
    toks[tid] = SH ? rr : list[e * TT + (rr < n_rows ? rr : row0)];
  }
  __syncthreads();

  const __bf16* pA[4];
#pragma unroll
  for (int i = 0; i < 4; ++i) {
    int s = w * 256 + i * 64 + lane;
    int r = s >> 3, k8 = (s & 7) ^ (r & 7);
    pA[i] = xb + (size_t)toks[r] * HH + k8 * 8;
  }
  // B assignment: one (row-pair, k8) per thread per operand
  const int bq = lane;             // row-pair 0..63 -> rows 2bq, 2bq+1
  const int bk8 = w;               // k8 0..7
  const float* pBg = Bg + n0 + 2 * bq;
  const float* pBu = Bu + n0 + 2 * bq;
  const int bs0 = 16 * bq + (bk8 ^ (bq & 7));   // slot(2bq, bk8); +8 for row 2bq+1

  f32x4 accg[4][4], accu[4][4];
  const f32x4 fz = {0.f, 0.f, 0.f, 0.f};
#pragma unroll
  for (int m = 0; m < 4; ++m)
#pragma unroll
    for (int n = 0; n < 4; ++n) { accg[m][n] = fz; accu[m][n] = fz; }

  const int wm = w >> 1, wn = w & 1;
  const int lr = lane & 15, l16 = lane >> 4;
  const int NT = HH / 64;          // 32

  float2 R0g[8], R0u[8], R1g[8], R1u[8];

  // NOTE: A gl_lds issued BEFORE B loads so any wait covering B also covers A.
#define GU_ISSUE(Rg_, Ru_, bb, tt)                                        \
  { const int kb_ = (tt) * 64;                                            \
    _Pragma("unroll") for (int i = 0; i < 4; ++i)                         \
      gl_lds16(pA[i] + kb_, &As[bb][w * 256 + i * 64]);                   \
    _Pragma("unroll") for (int j = 0; j < 8; ++j) {                       \
      Rg_[j] = *reinterpret_cast<const float2*>(                          \
          pBg + (size_t)(kb_ + bk8 * 8 + j) * ldw);                       \
      Ru_[j] = *reinterpret_cast<const float2*>(                          \
          pBu + (size_t)(kb_ + bk8 * 8 + j) * ldw);                       \
    } }

#define GU_PACK(Rg_, Ru_, bb)                                             \
  { uint4 q_;                                                             \
    q_.x = pk2(Rg_[0].x, Rg_[1].x); q_.y = pk2(Rg_[2].x, Rg_[3].x);       \
    q_.z = pk2(Rg_[4].x, Rg_[5].x); q_.w = pk2(Rg_[6].x, Rg_[7].x);       \
    Bgs[bb][bs0] = q_;                                                    \
    q_.x = pk2(Rg_[0].y, Rg_[1].y); q_.y = pk2(Rg_[2].y, Rg_[3].y);       \
    q_.z = pk2(Rg_[4].y, Rg_[5].y); q_.w = pk2(Rg_[6].y, Rg_[7].y);       \
    Bgs[bb][bs0 + 8] = q_;                                                \
    q_.x = pk2(Ru_[0].x, Ru_[1].x); q_.y = pk2(Ru_[2].x, Ru_[3].x);       \
    q_.z = pk2(Ru_[4].x, Ru_[5].x); q_.w = pk2(Ru_[6].x, Ru_[7].x);       \
    Bus[bb][bs0] = q_;                                                    \
    q_.x = pk2(Ru_[0].y, Ru_[1].y); q_.y = pk2(Ru_[2].y, Ru_[3].y);       \
    q_.z = pk2(Ru_[4].y, Ru_[5].y); q_.w = pk2(Ru_[6].y, Ru_[7].y);       \
    Bus[bb][bs0 + 8] = q_; }

#define GU_COMPUTE(bb)                                                    \
  { _Pragma("unroll") for (int ks = 0; ks < 2; ++ks) {                    \
      const int k8r = ks * 4 + l16;                                       \
      bf16x8 af[4], bg[4], bu[4];                                         \
      _Pragma("unroll") for (int m = 0; m < 4; ++m) {                     \
        int rw = wm * 64 + m * 16 + lr;                                   \
        af[m] = *reinterpret_cast<const bf16x8*>(                         \
            &As[bb][rw * 8 + (k8r ^ (rw & 7))]);                          \
      }                                                                   \
      _Pragma("unroll") for (int n = 0; n < 4; ++n) {                     \
        int cn = wn * 64 + n * 16 + lr;                                   \
        int sw_ = k8r ^ ((cn >> 1) & 7);                                  \
        bg[n] = *reinterpret_cast<const bf16x8*>(&Bgs[bb][cn * 8 + sw_]); \
        bu[n] = *reinterpret_cast<const bf16x8*>(&Bus[bb][cn * 8 + sw_]); \
      }                                                                   \
      _Pragma("unroll") for (int m = 0; m < 4; ++m)                       \
        _Pragma("unroll") for (int n = 0; n < 4; ++n) {                   \
          accg[m][n] = mfma16(af[m], bg[n], accg[m][n]);                  \
          accu[m][n] = mfma16(af[m], bu[n], accu[m][n]);                  \
        }                                                                 \
    } }

#define GU_STEP(bb, tcur, Rcg, Rcu, Rng, Rnu)                             \
  { GU_COMPUTE(bb)                                                        \
    __builtin_amdgcn_s_barrier();                                         \
    if ((tcur) + 2 < NT) { GU_ISSUE(Rcg, Rcu, bb, (tcur) + 2) }           \
    if ((tcur) + 1 < NT) {                                                \
      GU_PACK(Rng, Rnu, (bb) ^ 1)                                         \
      asm volatile("s_waitcnt lgkmcnt(0)" ::: "memory");                  \
      if ((tcur) + 2 < NT)                                                \
        asm volatile("s_waitcnt vmcnt(20)" ::: "memory");                 \
      else                                                                \
        asm volatile("s_waitcnt vmcnt(0)" ::: "memory");                  \
      __builtin_amdgcn_s_barrier();                                       \
    } }

  // prologue
  GU_ISSUE(R0g, R0u, 0, 0)
  GU_ISSUE(R1g, R1u, 1, 1)
  GU_PACK(R0g, R0u, 0)
  asm volatile("s_waitcnt lgkmcnt(0)" ::: "memory");
  asm volatile("s_waitcnt vmcnt(20)" ::: "memory");
  __builtin_amdgcn_s_barrier();

  for (int t = 0; t < NT; t += 2) {
    GU_STEP(0, t, R0g, R0u, R1g, R1u)
    GU_STEP(1, t + 1, R1g, R1u, R0g, R0u)
  }

#pragma unroll
  for (int m = 0; m < 4; ++m)
#pragma unroll
    for (int n = 0; n < 4; ++n)
#pragma unroll
      for (int q = 0; q < 4; ++q) {
        int rloc = wm * 64 + m * 16 + l16 * 4 + q;
        if (row0 + rloc >= n_rows) continue;
        int cloc = wn * 64 + n * 16 + lr;
        float g = accg[m][n][q], u = accu[m][n][q];
        float sv = g / (1.f + __expf(-g)) * u;
        outp[(size_t)(base + row0 + rloc) * Nt + (n0 + cloc)] = (__bf16)sv;
      }
#undef GU_ISSUE
#undef GU_PACK
#undef GU_COMPUTE
#undef GU_STEP
}

// ---- down GEMM: BM=256 BN=256 BK=64, direct fp32 B (reg-staged + pack) ----
__global__ __launch_bounds__(512)
void k_down6(const __bf16* __restrict__ a_buf, const __bf16* __restrict__ s_buf,
             const float* __restrict__ wd, const float* __restrict__ sd,
             const int* __restrict__ counts, const int* __restrict__ offs,
             const int* __restrict__ hdr, const int* __restrict__ dn_tab,
             __bf16* __restrict__ eo, float* __restrict__ out)
{
  const int nwg = hdr[1];
  const int orig = blockIdx.x;
  if (orig >= nwg) return;
  const int qq = nwg >> 3, r8 = nwg & 7, xcd = orig & 7;
  const int wgid = (xcd < r8 ? xcd * (qq + 1) : r8 * (qq + 1) + (xcd - r8) * qq)
                   + (orig >> 3);
  const int ent = dn_tab[wgid];
  const int e = ent >> 16, rt = (ent >> 8) & 255, nt = ent & 255;
  const bool SH = (e == EE);
  const int Kdim = SH ? IIS : II;
  const int n_rows = SH ? TT : counts[e];
  const int row0 = rt * 256, n0 = nt * 256;
  if (row0 >= n_rows) return;
  const int base = SH ? 0 : offs[e];
  const __bf16* Ain = SH ? s_buf : a_buf + (size_t)base * II;
  const float* Bd = SH ? sd : wd + (size_t)e * (size_t)II * HH;  // [k][n], ld HH

  __shared__ uint4 As[2][2048];   // 64KB
  __shared__ uint4 Bs[2][2048];   // 64KB

  const int tid = threadIdx.x;
  const int lane = tid & 63, w = tid >> 6;
  const int wm = w >> 2, wn = w & 3;
  const int lr = lane & 15, l16 = lane >> 4;

  const __bf16* pA[4];
#pragma unroll
  for (int i = 0; i < 4; ++i) {
    int s = w * 256 + i * 64 + lane;
    int r = s >> 3, k8 = (s & 7) ^ (r & 7);
    int rr = row0 + r; if (rr >= n_rows) rr = row0;
    pA[i] = Ain + (size_t)rr * Kdim + k8 * 8;
  }
  const int dq = (w & 1) * 64 + lane;   // row-pair 0..127 -> rows 2dq,2dq+1
  const int dk0 = (w >> 1) * 2;         // k8 in {dk0, dk0+1}
  const float* pBd = Bd + n0 + 2 * dq;
  const int ds0 = 16 * dq + (dk0 ^ (dq & 7));        // slot(2dq, dk0)
  const int ds1 = 16 * dq + ((dk0 + 1) ^ (dq & 7));  // slot(2dq, dk0+1)

  f32x4 acc[8][4];
  const f32x4 fz = {0.f, 0.f, 0.f, 0.f};
#pragma unroll
  for (int m = 0; m < 8; ++m)
#pragma unroll
    for (int n = 0; n < 4; ++n) acc[m][n] = fz;

  const int NTS = Kdim >> 6;  // 22 or 44 (even)
  float2 R0d[16], R1d[16];

#define DN_ISSUE(Rd_, bb, tt)                                             \
  { const int kb_ = (tt) * 64;                                            \
    _Pragma("unroll") for (int i = 0; i < 4; ++i)                         \
      gl_lds16(pA[i] + kb_, &As[bb][w * 256 + i * 64]);                   \
    _Pragma("unroll") for (int j = 0; j < 8; ++j) {                       \
      Rd_[j] = *reinterpret_cast<const float2*>(                          \
          pBd + (size_t)(kb_ + dk0 * 8 + j) * HH);                        \
      Rd_[8 + j] = *reinterpret_cast<const float2*>(                      \
          pBd + (size_t)(kb_ + (dk0 + 1) * 8 + j) * HH);                  \
    } }

#define DN_PACK(Rd_, bb)                                                  \
  { uint4 q_;                                                             \
    q_.x = pk2(Rd_[0].x, Rd_[1].x); q_.y = pk2(Rd_[2].x, Rd_[3].x);       \
    q_.z = pk2(Rd_[4].x, Rd_[5].x); q_.w = pk2(Rd_[6].x, Rd_[7].x);       \
    Bs[bb][ds0] = q_;                                                     \
    q_.x = pk2(Rd_[0].y, Rd_[1].y); q_.y = pk2(Rd_[2].y, Rd_[3].y);       \
    q_.z = pk2(Rd_[4].y, Rd_[5].y); q_.w = pk2(Rd_[6].y, Rd_[7].y);       \
    Bs[bb][ds0 + 8] = q_;                                                 \
    q_.x = pk2(Rd_[8].x, Rd_[9].x); q_.y = pk2(Rd_[10].x, Rd_[11].x);     \
    q_.z = pk2(Rd_[12].x, Rd_[13].x); q_.w = pk2(Rd_[14].x, Rd_[15].x);   \
    Bs[bb][ds1] = q_;                                                     \
    q_.x = pk2(Rd_[8].y, Rd_[9].y); q_.y = pk2(Rd_[10].y, Rd_[11].y);     \
    q_.z = pk2(Rd_[12].y, Rd_[13].y); q_.w = pk2(Rd_[14].y, Rd_[15].y);   \
    Bs[bb][ds1 + 8] = q_; }

#define DN_COMPUTE(bb)                                                    \
  { _Pragma("unroll") for (int ks = 0; ks < 2; ++ks) {                    \
      const int k8r = ks * 4 + l16;                                       \
      bf16x8 af[8], bb_[4];                                               \
      _Pragma("unroll") for (int m = 0; m < 8; ++m) {                     \
        int rw = wm * 128 + m * 16 + lr;                                  \
        af[m] = *reinterpret_cast<const bf16x8*>(                         \
            &As[bb][rw * 8 + (k8r ^ (rw & 7))]);                          \
      }                                                                   \
      _Pragma("unroll") for (int n = 0; n < 4; ++n) {                     \
        int cn = wn * 64 + n * 16 + lr;                                   \
        bb_[n] = *reinterpret_cast<const bf16x8*>(                        \
            &Bs[bb][cn * 8 + (k8r ^ ((cn >> 1) & 7))]);                   \
      }                                                                   \
      _Pragma("unroll") for (int m = 0; m < 8; ++m)                       \
        _Pragma("unroll") for (int n = 0; n < 4; ++n)                     \
          acc[m][n] = mfma16(af[m], bb_[n], acc[m][n]);                   \
    } }

#define DN_STEP(bb, tcur, Rc, Rn)                                         \
  { DN_COMPUTE(bb)                                                        \
    __builtin_amdgcn_s_barrier();                                         \
    if ((tcur) + 2 < NTS) { DN_ISSUE(Rc, bb, (tcur) + 2) }                \
    if ((tcur) + 1 < NTS) {                                               \
      DN_PACK(Rn, (bb) ^ 1)                                               \
      asm volatile("s_waitcnt lgkmcnt(0)" ::: "memory");                  \
      if ((tcur) + 2 < NTS)                                               \
        asm volatile("s_waitcnt vmcnt(20)" ::: "memory");                 \
      else                                                                \
        asm volatile("s_waitcnt vmcnt(0)" ::: "memory");                  \
      __builtin_amdgcn_s_barrier();                                       \
    } }

  // prologue
  DN_ISSUE(R0d, 0, 0)
  DN_ISSUE(R1d, 1, 1)
  DN_PACK(R0d, 0)
  asm volatile("s_waitcnt lgkmcnt(0)" ::: "memory");
  asm volatile("s_waitcnt vmcnt(20)" ::: "memory");
  __builtin_amdgcn_s_barrier();

  for (int t = 0; t < NTS; t += 2) {
    DN_STEP(0, t, R0d, R1d)
    DN_STEP(1, t + 1, R1d, R0d)
  }

#pragma unroll
  for (int m = 0; m < 8; ++m)
#pragma unroll
    for (int n = 0; n < 4; ++n)
#pragma unroll
      for (int q = 0; q < 4; ++q) {
        int rloc = wm * 128 + m * 16 + l16 * 4 + q;
        int cloc = wn * 64 + n * 16 + lr;
        if (SH) {
          out[(size_t)(row0 + rloc) * HH + (n0 + cloc)] = acc[m][n][q];
        } else if (row0 + rloc < n_rows) {
          eo[(size_t)(base + row0 + rloc) * HH + (n0 + cloc)] = (__bf16)acc[m][n][q];
        }
      }
#undef DN_ISSUE
#undef DN_PACK
#undef DN_COMPUTE
#undef DN_STEP
}

// ------------- weighted combine: out += sum_j w_j * eo[row_j] -------------
__global__ __launch_bounds__(256)
void k_combine(const __bf16* __restrict__ eo, const int* __restrict__ row_of,
               const float* __restrict__ wvec, float* __restrict__ out)
{
  const int t = blockIdx.x, tid = threadIdx.x;
  const int h0 = tid * 8;
  float acc[8];
  float4* op = reinterpret_cast<float4*>(out + (size_t)t * HH + h0);
  float4 o0 = op[0], o1 = op[1];
  acc[0] = o0.x; acc[1] = o0.y; acc[2] = o0.z; acc[3] = o0.w;
  acc[4] = o1.x; acc[5] = o1.y; acc[6] = o1.z; acc[7] = o1.w;
#pragma unroll
  for (int j = 0; j < 4; ++j) {
    int r = row_of[t * 4 + j];
    float wj = wvec[t * 4 + j];
    uint4 v = *reinterpret_cast<const uint4*>(eo + (size_t)r * HH + h0);
    unsigned int ws4[4] = {v.x, v.y, v.z, v.w};
#pragma unroll
    for (int q = 0; q < 4; ++q) {
      acc[q * 2 + 0] += wj * bf2f((unsigned short)(ws4[q] & 0xffffu));
      acc[q * 2 + 1] += wj * bf2f((unsigned short)(ws4[q] >> 16));
    }
  }
  o0.x = acc[0]; o0.y = acc[1]; o0.z = acc[2]; o0.w = acc[3];
  o1.x = acc[4]; o1.y = acc[5]; o1.z = acc[6]; o1.w = acc[7];
  op[0] = o0; op[1] = o1;
}

extern "C" void kernel_launch(void* const* d_in, const int* in_sizes, int n_in,
                              void* d_out, int out_size, void* d_ws, size_t ws_size,
                              hipStream_t stream) {
  const float* x  = (const float*)d_in[0];
  const float* gw = (const float*)d_in[1];
  const float* gb = (const float*)d_in[2];
  const float* wg = (const float*)d_in[3];
  const float* wu = (const float*)d_in[4];
  const float* wd = (const float*)d_in[5];
  const float* sg = (const float*)d_in[6];
  const float* su = (const float*)d_in[7];
  const float* sd = (const float*)d_in[8];
  float* out = (float*)d_out;

  char* ws = (char*)d_ws;
  size_t off = 0;
  auto carve = [&](size_t bytes) {
    off = (off + 255) & ~(size_t)255;
    void* p = (void*)(ws + off);
    off += bytes;
    return p;
  };
  int*    topk_idx = (int*)carve((size_t)TT * KK * 4);
  float*  wvec     = (float*)carve((size_t)TT * KK * 4);
  int*    counts   = (int*)carve(EE * 4);
  int*    offs     = (int*)carve(EE * 4);
  int*    list     = (int*)carve((size_t)EE * TT * 4);
  int*    row_of   = (int*)carve((size_t)TT * KK * 4);
  int*    hdr      = (int*)carve(64);
  int*    gu_tab   = (int*)carve(GU_MAXT * 4);
  int*    dn_tab   = (int*)carve(DN_MAXT * 4);
  __bf16* xb       = (__bf16*)carve((size_t)TT * HH * 2);
  __bf16* a_buf    = (__bf16*)carve((size_t)TT * KK * II * 2);
  __bf16* s_buf    = (__bf16*)carve((size_t)TT * IIS * 2);
  __bf16* eo       = (__bf16*)carve((size_t)TT * KK * HH * 2);
  (void)ws_size;  // ~38 MB needed, well under provided workspace

  k_route<<<TT, 256, 0, stream>>>(x, gw, gb, topk_idx, wvec, xb);
  k_lists<<<1, 1024, 0, stream>>>(topk_idx, counts, offs, list, row_of,
                                  hdr, gu_tab, dn_tab);
  // gate/up GEMM: direct fp32 weights, on-the-fly convert+transpose in LDS
  k_gu5<<<GU_MAXT, 512, 0, stream>>>(
      xb, wg, wu, sg, su, counts, offs, list, hdr, gu_tab, a_buf, s_buf);
  // down GEMM: direct fp32 weights (routed -> eo, shared -> out)
  k_down6<<<DN_MAXT, 512, 0, stream>>>(
      a_buf, s_buf, wd, sd, counts, offs, hdr, dn_tab, eo, out);
  k_combine<<<TT, 256, 0, stream>>>(eo, row_of, wvec, out);
}

// Round 11
// 1623.753 us; speedup vs baseline: 1.0016x; 1.0016x over previous
//
#include <hip/hip_runtime.h>
#include <hip/hip_bf16.h>

#define TT 1024
#define HH 2048
#define EE 16
#define KK 4
#define II 1408
#define IIS 2816
#define GU_MAXT 448
#define DN_MAXT 288

typedef __bf16 bf16x8 __attribute__((ext_vector_type(8)));
typedef float f32x4 __attribute__((ext_vector_type(4)));

__device__ __forceinline__ f32x4 mfma16(bf16x8 a, bf16x8 b, f32x4 c) {
  return __builtin_amdgcn_mfma_f32_16x16x32_bf16(a, b, c, 0, 0, 0);
}

__device__ __forceinline__ void gl_lds16(const void* g, void* l) {
  __builtin_amdgcn_global_load_lds(
      (const __attribute__((address_space(1))) void*)g,
      (__attribute__((address_space(3))) void*)l, 16, 0, 0);
}

__device__ __forceinline__ unsigned int pk2(float a, float b) {
  unsigned short lo = __builtin_bit_cast(unsigned short, (__bf16)a);
  unsigned short hi = __builtin_bit_cast(unsigned short, (__bf16)b);
  return (unsigned int)lo | ((unsigned int)hi << 16);
}

__device__ __forceinline__ float bf2f(unsigned short u) {
  return __builtin_bit_cast(float, (unsigned int)u << 16);
}

// ---------------- routing: logits + noaux_tc top-k ----------------
__global__ __launch_bounds__(256)
void k_route(const float* __restrict__ x, const float* __restrict__ gw,
             const float* __restrict__ gb,
             int* __restrict__ topk_idx, float* __restrict__ wvec,
             __bf16* __restrict__ xb)
{
  const int t = blockIdx.x;
  const int tid = threadIdx.x;
  float a[EE];
#pragma unroll
  for (int e = 0; e < EE; ++e) a[e] = 0.f;
  for (int h = tid; h < HH; h += 256) {
    float xv = x[(size_t)t * HH + h];
    xb[(size_t)t * HH + h] = (__bf16)xv;
#pragma unroll
    for (int e = 0; e < EE; ++e) a[e] += xv * gw[e * HH + h];
  }
  __shared__ float part[4][EE];
  const int lane = tid & 63, wv = tid >> 6;
#pragma unroll
  for (int e = 0; e < EE; ++e) {
    float v = a[e];
#pragma unroll
    for (int off = 32; off > 0; off >>= 1) v += __shfl_xor(v, off);
    if (lane == 0) part[wv][e] = v;
  }
  __syncthreads();
  if (tid == 0) {
    float sc[EE], sb[EE];
    for (int e = 0; e < EE; ++e) {
      float lg = part[0][e] + part[1][e] + part[2][e] + part[3][e];
      sc[e] = 1.f / (1.f + expf(-lg));
      sb[e] = sc[e] + gb[e];
    }
    float gsc[4];
    for (int g = 0; g < 4; ++g) {
      float m1 = -1e30f, m2 = -1e30f;
      for (int j = 0; j < 4; ++j) {
        float v = sb[g * 4 + j];
        if (v > m1) { m2 = m1; m1 = v; } else if (v > m2) { m2 = v; }
      }
      gsc[g] = m1 + m2;
    }
    int g1 = 0; float b1 = gsc[0];
    for (int g = 1; g < 4; ++g) if (gsc[g] > b1) { b1 = gsc[g]; g1 = g; }
    int g2 = 0; float b2 = -1e30f;
    for (int g = 0; g < 4; ++g) if (g != g1 && gsc[g] > b2) { b2 = gsc[g]; g2 = g; }
    bool used[EE];
    for (int e = 0; e < EE; ++e) used[e] = !(((e >> 2) == g1) || ((e >> 2) == g2));
    int sel[KK]; float sw[KK]; float ssum = 0.f;
    for (int j = 0; j < KK; ++j) {
      float best = -1e30f; int bi = 0;
      for (int e = 0; e < EE; ++e)
        if (!used[e] && sb[e] > best) { best = sb[e]; bi = e; }
      used[bi] = true; sel[j] = bi; sw[j] = sc[bi]; ssum += sc[bi];
    }
    float s = 2.5f / (ssum + 1e-20f);
    for (int j = 0; j < KK; ++j) {
      topk_idx[t * KK + j] = sel[j];
      wvec[t * KK + j] = sw[j] * s;
    }
  }
}

// ------ deterministic expert lists + compacted tile tables -------
// gu: BM=256 x BN=128; dn: BM=256 x BN=256
__global__ __launch_bounds__(1024)
void k_lists(const int* __restrict__ topk_idx,
             int* __restrict__ counts, int* __restrict__ offs,
             int* __restrict__ list, int* __restrict__ row_of,
             int* __restrict__ hdr, int* __restrict__ gu_tab,
             int* __restrict__ dn_tab)
{
  const int t = threadIdx.x;
  const int lane = t & 63, wv = t >> 6;
  const int e0 = topk_idx[t * 4 + 0], e1 = topk_idx[t * 4 + 1],
            e2 = topk_idx[t * 4 + 2], e3 = topk_idx[t * 4 + 3];
  __shared__ int wtot[16];
  __shared__ int cnt[EE];
  __shared__ int offsh[EE + 1];
  __shared__ int rtn[EE], gpre[EE + 1], dpre[EE + 1];
  int p0 = 0, p1 = 0, p2 = 0, p3 = 0;
  for (int e = 0; e < EE; ++e) {
    bool f = (e0 == e) || (e1 == e) || (e2 == e) || (e3 == e);
    unsigned long long b = __ballot(f);
    if (lane == 0) wtot[wv] = __popcll(b);
    __syncthreads();
    int wo = 0;
    for (int w2 = 0; w2 < wv; ++w2) wo += wtot[w2];
    if (f) {
      int pos = wo + __popcll(b & ((1ull << lane) - 1ull));
      list[e * TT + pos] = t;
      if (e0 == e) p0 = pos; else if (e1 == e) p1 = pos;
      else if (e2 == e) p2 = pos; else p3 = pos;
    }
    if (t == 0) {
      int tot = 0;
      for (int w2 = 0; w2 < 16; ++w2) tot += wtot[w2];
      cnt[e] = tot;
    }
    __syncthreads();
  }
  if (t == 0) {
    offsh[0] = 0;
    for (int e = 0; e < EE; ++e) offsh[e + 1] = offsh[e] + cnt[e];
    for (int e = 0; e < EE; ++e) { counts[e] = cnt[e]; offs[e] = offsh[e]; }
    gpre[0] = 0; dpre[0] = 0;
    for (int e = 0; e < EE; ++e) {
      int rr = (cnt[e] + 255) >> 8;           // ceil(cnt/256)
      rtn[e] = rr;
      gpre[e + 1] = gpre[e] + rr * (II / 128);
      dpre[e + 1] = dpre[e] + rr * (HH / 256);
    }
    hdr[0] = gpre[EE] + 4 * (IIS / 128);      // shared: 4 row-tiles of 256
    hdr[1] = dpre[EE] + 4 * (HH / 256);
  }
  __syncthreads();
  row_of[t * 4 + 0] = offsh[e0] + p0;
  row_of[t * 4 + 1] = offsh[e1] + p1;
  row_of[t * 4 + 2] = offsh[e2] + p2;
  row_of[t * 4 + 3] = offsh[e3] + p3;
  if (t < EE) {
    int rr = rtn[t];
    int p = gpre[t];
    for (int nt = 0; nt < II / 128; ++nt)
      for (int rt = 0; rt < rr; ++rt) gu_tab[p++] = (t << 16) | (rt << 8) | nt;
    p = dpre[t];
    for (int nt = 0; nt < HH / 256; ++nt)
      for (int rt = 0; rt < rr; ++rt) dn_tab[p++] = (t << 16) | (rt << 8) | nt;
  } else if (t == EE) {
    int p = gpre[EE];
    for (int nt = 0; nt < IIS / 128; ++nt)
      for (int rt = 0; rt < 4; ++rt) gu_tab[p++] = (EE << 16) | (rt << 8) | nt;
    p = dpre[EE];
    for (int nt = 0; nt < HH / 256; ++nt)
      for (int rt = 0; rt < 4; ++rt) dn_tab[p++] = (EE << 16) | (rt << 8) | nt;
  }
}

// ---- gate/up GEMM: BM=256 BN=128 BK=64, direct fp32 B (reg-staged + pack) ----
// A image (gl_lds, pre-swizzled src): slot s -> (r=s>>3, k8=(s&7)^(r&7)).
// B image (ds_write): slot(r,k8) = r*8 + (k8 ^ ((r>>1)&7)) -- transposed write
// conflict-free (8-way swz spread), fragment read 2-way (free).
// __launch_bounds__(512, 2): 2 waves/EU -> 256-VGPR cap (fixes r9 spill).
__global__ __launch_bounds__(512, 2)
void k_gu5(const __bf16* __restrict__ xb,
           const float* __restrict__ wg, const float* __restrict__ wu,
           const float* __restrict__ sg, const float* __restrict__ su,
           const int* __restrict__ counts, const int* __restrict__ offs,
           const int* __restrict__ list, const int* __restrict__ hdr,
           const int* __restrict__ gu_tab,
           __bf16* __restrict__ a_buf, __bf16* __restrict__ s_buf)
{
  const int nwg = hdr[0];
  const int orig = blockIdx.x;
  if (orig >= nwg) return;
  const int qq = nwg >> 3, r8 = nwg & 7, xcd = orig & 7;
  const int wgid = (xcd < r8 ? xcd * (qq + 1) : r8 * (qq + 1) + (xcd - r8) * qq)
                   + (orig >> 3);
  const int ent = gu_tab[wgid];
  const int e = ent >> 16, rt = (ent >> 8) & 255, nt = ent & 255;
  const bool SH = (e == EE);
  const int Nt = SH ? IIS : II;
  const int ldw = Nt;
  const int n0 = nt * 128, row0 = rt * 256;
  const int n_rows = SH ? TT : counts[e];
  if (row0 >= n_rows) return;
  const int base = SH ? 0 : offs[e];
  const float* Bg = SH ? sg : wg + (size_t)e * HH * II;   // [k][n] fp32
  const float* Bu = SH ? su : wu + (size_t)e * HH * II;
  __bf16* outp = SH ? s_buf : a_buf;

  __shared__ uint4 As[2][2048];    // 64KB
  __shared__ uint4 Bgs[2][1024];   // 32KB
  __shared__ uint4 Bus[2][1024];   // 32KB
  __shared__ int toks[256];

  const int tid = threadIdx.x;
  const int lane = tid & 63, w = tid >> 6;
  if (tid < 256) {
    int rr = row0 + tid;
    toks[tid] = SH ? rr : list[e * TT + (rr < n_rows ? rr : row0)];
  }
  __syncthreads();

  const __bf16* pA[4];
#pragma unroll
  for (int i = 0; i < 4; ++i) {
    int s = w * 256 + i * 64 + lane;
    int r = s >> 3, k8 = (s & 7) ^ (r & 7);
    pA[i] = xb + (size_t)toks[r] * HH + k8 * 8;
  }
  // B assignment: one (row-pair, k8) per thread per operand
  const int bq = lane;             // row-pair 0..63 -> rows 2bq, 2bq+1
  const int bk8 = w;               // k8 0..7
  const float* pBg = Bg + n0 + 2 * bq;
  const float* pBu = Bu + n0 + 2 * bq;
  const int bs0 = 16 * bq + (bk8 ^ (bq & 7));   // slot(2bq, bk8); +8 for row 2bq+1

  f32x4 accg[4][4], accu[4][4];
  const f32x4 fz = {0.f, 0.f, 0.f, 0.f};
#pragma unroll
  for (int m = 0; m < 4; ++m)
#pragma unroll
    for (int n = 0; n < 4; ++n) { accg[m][n] = fz; accu[m][n] = fz; }

  const int wm = w >> 1, wn = w & 1;
  const int lr = lane & 15, l16 = lane >> 4;
  const int NT = HH / 64;          // 32

  float2 R0g[8], R0u[8], R1g[8], R1u[8];

  // NOTE: A gl_lds issued BEFORE B loads so any wait covering B also covers A.
#define GU_ISSUE(Rg_, Ru_, bb, tt)                                        \
  { const int kb_ = (tt) * 64;                                            \
    _Pragma("unroll") for (int i = 0; i < 4; ++i)                         \
      gl_lds16(pA[i] + kb_, &As[bb][w * 256 + i * 64]);                   \
    _Pragma("unroll") for (int j = 0; j < 8; ++j) {                       \
      Rg_[j] = *reinterpret_cast<const float2*>(                          \
          pBg + (size_t)(kb_ + bk8 * 8 + j) * ldw);                       \
      Ru_[j] = *reinterpret_cast<const float2*>(                          \
          pBu + (size_t)(kb_ + bk8 * 8 + j) * ldw);                       \
    } }

#define GU_PACK(Rg_, Ru_, bb)                                             \
  { uint4 q_;                                                             \
    q_.x = pk2(Rg_[0].x, Rg_[1].x); q_.y = pk2(Rg_[2].x, Rg_[3].x);       \
    q_.z = pk2(Rg_[4].x, Rg_[5].x); q_.w = pk2(Rg_[6].x, Rg_[7].x);       \
    Bgs[bb][bs0] = q_;                                                    \
    q_.x = pk2(Rg_[0].y, Rg_[1].y); q_.y = pk2(Rg_[2].y, Rg_[3].y);       \
    q_.z = pk2(Rg_[4].y, Rg_[5].y); q_.w = pk2(Rg_[6].y, Rg_[7].y);       \
    Bgs[bb][bs0 + 8] = q_;                                                \
    q_.x = pk2(Ru_[0].x, Ru_[1].x); q_.y = pk2(Ru_[2].x, Ru_[3].x);       \
    q_.z = pk2(Ru_[4].x, Ru_[5].x); q_.w = pk2(Ru_[6].x, Ru_[7].x);       \
    Bus[bb][bs0] = q_;                                                    \
    q_.x = pk2(Ru_[0].y, Ru_[1].y); q_.y = pk2(Ru_[2].y, Ru_[3].y);       \
    q_.z = pk2(Ru_[4].y, Ru_[5].y); q_.w = pk2(Ru_[6].y, Ru_[7].y);       \
    Bus[bb][bs0 + 8] = q_; }

#define GU_COMPUTE(bb)                                                    \
  { _Pragma("unroll") for (int ks = 0; ks < 2; ++ks) {                    \
      const int k8r = ks * 4 + l16;                                       \
      bf16x8 af[4], bg[4], bu[4];                                         \
      _Pragma("unroll") for (int m = 0; m < 4; ++m) {                     \
        int rw = wm * 64 + m * 16 + lr;                                   \
        af[m] = *reinterpret_cast<const bf16x8*>(                         \
            &As[bb][rw * 8 + (k8r ^ (rw & 7))]);                          \
      }                                                                   \
      _Pragma("unroll") for (int n = 0; n < 4; ++n) {                     \
        int cn = wn * 64 + n * 16 + lr;                                   \
        int sw_ = k8r ^ ((cn >> 1) & 7);                                  \
        bg[n] = *reinterpret_cast<const bf16x8*>(&Bgs[bb][cn * 8 + sw_]); \
        bu[n] = *reinterpret_cast<const bf16x8*>(&Bus[bb][cn * 8 + sw_]); \
      }                                                                   \
      _Pragma("unroll") for (int m = 0; m < 4; ++m)                       \
        _Pragma("unroll") for (int n = 0; n < 4; ++n) {                   \
          accg[m][n] = mfma16(af[m], bg[n], accg[m][n]);                  \
          accu[m][n] = mfma16(af[m], bu[n], accu[m][n]);                  \
        }                                                                 \
    } }

#define GU_STEP(bb, tcur, Rcg, Rcu, Rng, Rnu)                             \
  { GU_COMPUTE(bb)                                                        \
    __builtin_amdgcn_s_barrier();                                         \
    if ((tcur) + 2 < NT) { GU_ISSUE(Rcg, Rcu, bb, (tcur) + 2) }           \
    if ((tcur) + 1 < NT) {                                                \
      GU_PACK(Rng, Rnu, (bb) ^ 1)                                         \
      asm volatile("s_waitcnt lgkmcnt(0)" ::: "memory");                  \
      if ((tcur) + 2 < NT)                                                \
        asm volatile("s_waitcnt vmcnt(20)" ::: "memory");                 \
      else                                                                \
        asm volatile("s_waitcnt vmcnt(0)" ::: "memory");                  \
      __builtin_amdgcn_s_barrier();                                       \
    } }

  // prologue
  GU_ISSUE(R0g, R0u, 0, 0)
  GU_ISSUE(R1g, R1u, 1, 1)
  GU_PACK(R0g, R0u, 0)
  asm volatile("s_waitcnt lgkmcnt(0)" ::: "memory");
  asm volatile("s_waitcnt vmcnt(20)" ::: "memory");
  __builtin_amdgcn_s_barrier();

  for (int t = 0; t < NT; t += 2) {
    GU_STEP(0, t, R0g, R0u, R1g, R1u)
    GU_STEP(1, t + 1, R1g, R1u, R0g, R0u)
  }

#pragma unroll
  for (int m = 0; m < 4; ++m)
#pragma unroll
    for (int n = 0; n < 4; ++n)
#pragma unroll
      for (int q = 0; q < 4; ++q) {
        int rloc = wm * 64 + m * 16 + l16 * 4 + q;
        if (row0 + rloc >= n_rows) continue;
        int cloc = wn * 64 + n * 16 + lr;
        float g = accg[m][n][q], u = accu[m][n][q];
        float sv = g / (1.f + __expf(-g)) * u;
        outp[(size_t)(base + row0 + rloc) * Nt + (n0 + cloc)] = (__bf16)sv;
      }
#undef GU_ISSUE
#undef GU_PACK
#undef GU_COMPUTE
#undef GU_STEP
}

// ---- down GEMM: BM=256 BN=256 BK=64, direct fp32 B (reg-staged + pack) ----
__global__ __launch_bounds__(512, 2)
void k_down6(const __bf16* __restrict__ a_buf, const __bf16* __restrict__ s_buf,
             const float* __restrict__ wd, const float* __restrict__ sd,
             const int* __restrict__ counts, const int* __restrict__ offs,
             const int* __restrict__ hdr, const int* __restrict__ dn_tab,
             __bf16* __restrict__ eo, float* __restrict__ out)
{
  const int nwg = hdr[1];
  const int orig = blockIdx.x;
  if (orig >= nwg) return;
  const int qq = nwg >> 3, r8 = nwg & 7, xcd = orig & 7;
  const int wgid = (xcd < r8 ? xcd * (qq + 1) : r8 * (qq + 1) + (xcd - r8) * qq)
                   + (orig >> 3);
  const int ent = dn_tab[wgid];
  const int e = ent >> 16, rt = (ent >> 8) & 255, nt = ent & 255;
  const bool SH = (e == EE);
  const int Kdim = SH ? IIS : II;
  const int n_rows = SH ? TT : counts[e];
  const int row0 = rt * 256, n0 = nt * 256;
  if (row0 >= n_rows) return;
  const int base = SH ? 0 : offs[e];
  const __bf16* Ain = SH ? s_buf : a_buf + (size_t)base * II;
  const float* Bd = SH ? sd : wd + (size_t)e * (size_t)II * HH;  // [k][n], ld HH

  __shared__ uint4 As[2][2048];   // 64KB
  __shared__ uint4 Bs[2][2048];   // 64KB

  const int tid = threadIdx.x;
  const int lane = tid & 63, w = tid >> 6;
  const int wm = w >> 2, wn = w & 3;
  const int lr = lane & 15, l16 = lane >> 4;

  const __bf16* pA[4];
#pragma unroll
  for (int i = 0; i < 4; ++i) {
    int s = w * 256 + i * 64 + lane;
    int r = s >> 3, k8 = (s & 7) ^ (r & 7);
    int rr = row0 + r; if (rr >= n_rows) rr = row0;
    pA[i] = Ain + (size_t)rr * Kdim + k8 * 8;
  }
  const int dq = (w & 1) * 64 + lane;   // row-pair 0..127 -> rows 2dq,2dq+1
  const int dk0 = (w >> 1) * 2;         // k8 in {dk0, dk0+1}
  const float* pBd = Bd + n0 + 2 * dq;
  const int ds0 = 16 * dq + (dk0 ^ (dq & 7));        // slot(2dq, dk0)
  const int ds1 = 16 * dq + ((dk0 + 1) ^ (dq & 7));  // slot(2dq, dk0+1)

  f32x4 acc[8][4];
  const f32x4 fz = {0.f, 0.f, 0.f, 0.f};
#pragma unroll
  for (int m = 0; m < 8; ++m)
#pragma unroll
    for (int n = 0; n < 4; ++n) acc[m][n] = fz;

  const int NTS = Kdim >> 6;  // 22 or 44 (even)
  float2 R0d[16], R1d[16];

#define DN_ISSUE(Rd_, bb, tt)                                             \
  { const int kb_ = (tt) * 64;                                            \
    _Pragma("unroll") for (int i = 0; i < 4; ++i)                         \
      gl_lds16(pA[i] + kb_, &As[bb][w * 256 + i * 64]);                   \
    _Pragma("unroll") for (int j = 0; j < 8; ++j) {                       \
      Rd_[j] = *reinterpret_cast<const float2*>(                          \
          pBd + (size_t)(kb_ + dk0 * 8 + j) * HH);                        \
      Rd_[8 + j] = *reinterpret_cast<const float2*>(                      \
          pBd + (size_t)(kb_ + (dk0 + 1) * 8 + j) * HH);                  \
    } }

#define DN_PACK(Rd_, bb)                                                  \
  { uint4 q_;                                                             \
    q_.x = pk2(Rd_[0].x, Rd_[1].x); q_.y = pk2(Rd_[2].x, Rd_[3].x);       \
    q_.z = pk2(Rd_[4].x, Rd_[5].x); q_.w = pk2(Rd_[6].x, Rd_[7].x);       \
    Bs[bb][ds0] = q_;                                                     \
    q_.x = pk2(Rd_[0].y, Rd_[1].y); q_.y = pk2(Rd_[2].y, Rd_[3].y);       \
    q_.z = pk2(Rd_[4].y, Rd_[5].y); q_.w = pk2(Rd_[6].y, Rd_[7].y);       \
    Bs[bb][ds0 + 8] = q_;                                                 \
    q_.x = pk2(Rd_[8].x, Rd_[9].x); q_.y = pk2(Rd_[10].x, Rd_[11].x);     \
    q_.z = pk2(Rd_[12].x, Rd_[13].x); q_.w = pk2(Rd_[14].x, Rd_[15].x);   \
    Bs[bb][ds1] = q_;                                                     \
    q_.x = pk2(Rd_[8].y, Rd_[9].y); q_.y = pk2(Rd_[10].y, Rd_[11].y);     \
    q_.z = pk2(Rd_[12].y, Rd_[13].y); q_.w = pk2(Rd_[14].y, Rd_[15].y);   \
    Bs[bb][ds1 + 8] = q_; }

#define DN_COMPUTE(bb)                                                    \
  { _Pragma("unroll") for (int ks = 0; ks < 2; ++ks) {                    \
      const int k8r = ks * 4 + l16;                                       \
      bf16x8 af[8], bb_[4];                                               \
      _Pragma("unroll") for (int m = 0; m < 8; ++m) {                     \
        int rw = wm * 128 + m * 16 + lr;                                  \
        af[m] = *reinterpret_cast<const bf16x8*>(                         \
            &As[bb][rw * 8 + (k8r ^ (rw & 7))]);                          \
      }                                                                   \
      _Pragma("unroll") for (int n = 0; n < 4; ++n) {                     \
        int cn = wn * 64 + n * 16 + lr;                                   \
        bb_[n] = *reinterpret_cast<const bf16x8*>(                        \
            &Bs[bb][cn * 8 + (k8r ^ ((cn >> 1) & 7))]);                   \
      }                                                                   \
      _Pragma("unroll") for (int m = 0; m < 8; ++m)                       \
        _Pragma("unroll") for (int n = 0; n < 4; ++n)                     \
          acc[m][n] = mfma16(af[m], bb_[n], acc[m][n]);                   \
    } }

#define DN_STEP(bb, tcur, Rc, Rn)                                         \
  { DN_COMPUTE(bb)                                                        \
    __builtin_amdgcn_s_barrier();                                         \
    if ((tcur) + 2 < NTS) { DN_ISSUE(Rc, bb, (tcur) + 2) }                \
    if ((tcur) + 1 < NTS) {                                               \
      DN_PACK(Rn, (bb) ^ 1)                                               \
      asm volatile("s_waitcnt lgkmcnt(0)" ::: "memory");                  \
      if ((tcur) + 2 < NTS)                                               \
        asm volatile("s_waitcnt vmcnt(20)" ::: "memory");                 \
      else                                                                \
        asm volatile("s_waitcnt vmcnt(0)" ::: "memory");                  \
      __builtin_amdgcn_s_barrier();                                       \
    } }

  // prologue
  DN_ISSUE(R0d, 0, 0)
  DN_ISSUE(R1d, 1, 1)
  DN_PACK(R0d, 0)
  asm volatile("s_waitcnt lgkmcnt(0)" ::: "memory");
  asm volatile("s_waitcnt vmcnt(20)" ::: "memory");
  __builtin_amdgcn_s_barrier();

  for (int t = 0; t < NTS; t += 2) {
    DN_STEP(0, t, R0d, R1d)
    DN_STEP(1, t + 1, R1d, R0d)
  }

#pragma unroll
  for (int m = 0; m < 8; ++m)
#pragma unroll
    for (int n = 0; n < 4; ++n)
#pragma unroll
      for (int q = 0; q < 4; ++q) {
        int rloc = wm * 128 + m * 16 + l16 * 4 + q;
        int cloc = wn * 64 + n * 16 + lr;
        if (SH) {
          out[(size_t)(row0 + rloc) * HH + (n0 + cloc)] = acc[m][n][q];
        } else if (row0 + rloc < n_rows) {
          eo[(size_t)(base + row0 + rloc) * HH + (n0 + cloc)] = (__bf16)acc[m][n][q];
        }
      }
#undef DN_ISSUE
#undef DN_PACK
#undef DN_COMPUTE
#undef DN_STEP
}

// ------------- weighted combine: out += sum_j w_j * eo[row_j] -------------
__global__ __launch_bounds__(256)
void k_combine(const __bf16* __restrict__ eo, const int* __restrict__ row_of,
               const float* __restrict__ wvec, float* __restrict__ out)
{
  const int t = blockIdx.x, tid = threadIdx.x;
  const int h0 = tid * 8;
  float acc[8];
  float4* op = reinterpret_cast<float4*>(out + (size_t)t * HH + h0);
  float4 o0 = op[0], o1 = op[1];
  acc[0] = o0.x; acc[1] = o0.y; acc[2] = o0.z; acc[3] = o0.w;
  acc[4] = o1.x; acc[5] = o1.y; acc[6] = o1.z; acc[7] = o1.w;
#pragma unroll
  for (int j = 0; j < 4; ++j) {
    int r = row_of[t * 4 + j];
    float wj = wvec[t * 4 + j];
    uint4 v = *reinterpret_cast<const uint4*>(eo + (size_t)r * HH + h0);
    unsigned int ws4[4] = {v.x, v.y, v.z, v.w};
#pragma unroll
    for (int q = 0; q < 4; ++q) {
      acc[q * 2 + 0] += wj * bf2f((unsigned short)(ws4[q] & 0xffffu));
      acc[q * 2 + 1] += wj * bf2f((unsigned short)(ws4[q] >> 16));
    }
  }
  o0.x = acc[0]; o0.y = acc[1]; o0.z = acc[2]; o0.w = acc[3];
  o1.x = acc[4]; o1.y = acc[5]; o1.z = acc[6]; o1.w = acc[7];
  op[0] = o0; op[1] = o1;
}

extern "C" void kernel_launch(void* const* d_in, const int* in_sizes, int n_in,
                              void* d_out, int out_size, void* d_ws, size_t ws_size,
                              hipStream_t stream) {
  const float* x  = (const float*)d_in[0];
  const float* gw = (const float*)d_in[1];
  const float* gb = (const float*)d_in[2];
  const float* wg = (const float*)d_in[3];
  const float* wu = (const float*)d_in[4];
  const float* wd = (const float*)d_in[5];
  const float* sg = (const float*)d_in[6];
  const float* su = (const float*)d_in[7];
  const float* sd = (const float*)d_in[8];
  float* out = (float*)d_out;

  char* ws = (char*)d_ws;
  size_t off = 0;
  auto carve = [&](size_t bytes) {
    off = (off + 255) & ~(size_t)255;
    void* p = (void*)(ws + off);
    off += bytes;
    return p;
  };
  int*    topk_idx = (int*)carve((size_t)TT * KK * 4);
  float*  wvec     = (float*)carve((size_t)TT * KK * 4);
  int*    counts   = (int*)carve(EE * 4);
  int*    offs     = (int*)carve(EE * 4);
  int*    list     = (int*)carve((size_t)EE * TT * 4);
  int*    row_of   = (int*)carve((size_t)TT * KK * 4);
  int*    hdr      = (int*)carve(64);
  int*    gu_tab   = (int*)carve(GU_MAXT * 4);
  int*    dn_tab   = (int*)carve(DN_MAXT * 4);
  __bf16* xb       = (__bf16*)carve((size_t)TT * HH * 2);
  __bf16* a_buf    = (__bf16*)carve((size_t)TT * KK * II * 2);
  __bf16* s_buf    = (__bf16*)carve((size_t)TT * IIS * 2);
  __bf16* eo       = (__bf16*)carve((size_t)TT * KK * HH * 2);
  (void)ws_size;  // ~38 MB needed, well under provided workspace

  k_route<<<TT, 256, 0, stream>>>(x, gw, gb, topk_idx, wvec, xb);
  k_lists<<<1, 1024, 0, stream>>>(topk_idx, counts, offs, list, row_of,
                                  hdr, gu_tab, dn_tab);
  // gate/up GEMM: direct fp32 weights, on-the-fly convert+transpose in LDS
  k_gu5<<<GU_MAXT, 512, 0, stream>>>(
      xb, wg, wu, sg, su, counts, offs, list, hdr, gu_tab, a_buf, s_buf);
  // down GEMM: direct fp32 weights (routed -> eo, shared -> out)
  k_down6<<<DN_MAXT, 512, 0, stream>>>(
      a_buf, s_buf, wd, sd, counts, offs, hdr, dn_tab, eo, out);
  k_combine<<<TT, 256, 0, stream>>>(eo, row_of, wvec, out);
}

// Round 12
// 1191.867 us; speedup vs baseline: 1.3646x; 1.3624x over previous
//
#include <hip/hip_runtime.h>
#include <hip/hip_bf16.h>

#define TT 1024
#define HH 2048
#define EE 16
#define KK 4
#define II 1408
#define IIS 2816
#define GU_MAXT 448
#define DN_MAXT 288

typedef __bf16 bf16x8 __attribute__((ext_vector_type(8)));
typedef float f32x4 __attribute__((ext_vector_type(4)));

__device__ __forceinline__ f32x4 mfma16(bf16x8 a, bf16x8 b, f32x4 c) {
  return __builtin_amdgcn_mfma_f32_16x16x32_bf16(a, b, c, 0, 0, 0);
}

__device__ __forceinline__ void gl_lds16(const void* g, void* l) {
  __builtin_amdgcn_global_load_lds(
      (const __attribute__((address_space(1))) void*)g,
      (__attribute__((address_space(3))) void*)l, 16, 0, 0);
}

__device__ __forceinline__ unsigned int pk2(float a, float b) {
  unsigned short lo = __builtin_bit_cast(unsigned short, (__bf16)a);
  unsigned short hi = __builtin_bit_cast(unsigned short, (__bf16)b);
  return (unsigned int)lo | ((unsigned int)hi << 16);
}

__device__ __forceinline__ float bf2f(unsigned short u) {
  return __builtin_bit_cast(float, (unsigned int)u << 16);
}

// ---------------- routing: logits + noaux_tc top-k ----------------
__global__ __launch_bounds__(256)
void k_route(const float* __restrict__ x, const float* __restrict__ gw,
             const float* __restrict__ gb,
             int* __restrict__ topk_idx, float* __restrict__ wvec,
             __bf16* __restrict__ xb)
{
  const int t = blockIdx.x;
  const int tid = threadIdx.x;
  float a[EE];
#pragma unroll
  for (int e = 0; e < EE; ++e) a[e] = 0.f;
  for (int h = tid; h < HH; h += 256) {
    float xv = x[(size_t)t * HH + h];
    xb[(size_t)t * HH + h] = (__bf16)xv;
#pragma unroll
    for (int e = 0; e < EE; ++e) a[e] += xv * gw[e * HH + h];
  }
  __shared__ float part[4][EE];
  const int lane = tid & 63, wv = tid >> 6;
#pragma unroll
  for (int e = 0; e < EE; ++e) {
    float v = a[e];
#pragma unroll
    for (int off = 32; off > 0; off >>= 1) v += __shfl_xor(v, off);
    if (lane == 0) part[wv][e] = v;
  }
  __syncthreads();
  if (tid == 0) {
    float sc[EE], sb[EE];
    for (int e = 0; e < EE; ++e) {
      float lg = part[0][e] + part[1][e] + part[2][e] + part[3][e];
      sc[e] = 1.f / (1.f + expf(-lg));
      sb[e] = sc[e] + gb[e];
    }
    float gsc[4];
    for (int g = 0; g < 4; ++g) {
      float m1 = -1e30f, m2 = -1e30f;
      for (int j = 0; j < 4; ++j) {
        float v = sb[g * 4 + j];
        if (v > m1) { m2 = m1; m1 = v; } else if (v > m2) { m2 = v; }
      }
      gsc[g] = m1 + m2;
    }
    int g1 = 0; float b1 = gsc[0];
    for (int g = 1; g < 4; ++g) if (gsc[g] > b1) { b1 = gsc[g]; g1 = g; }
    int g2 = 0; float b2 = -1e30f;
    for (int g = 0; g < 4; ++g) if (g != g1 && gsc[g] > b2) { b2 = gsc[g]; g2 = g; }
    bool used[EE];
    for (int e = 0; e < EE; ++e) used[e] = !(((e >> 2) == g1) || ((e >> 2) == g2));
    int sel[KK]; float sw[KK]; float ssum = 0.f;
    for (int j = 0; j < KK; ++j) {
      float best = -1e30f; int bi = 0;
      for (int e = 0; e < EE; ++e)
        if (!used[e] && sb[e] > best) { best = sb[e]; bi = e; }
      used[bi] = true; sel[j] = bi; sw[j] = sc[bi]; ssum += sc[bi];
    }
    float s = 2.5f / (ssum + 1e-20f);
    for (int j = 0; j < KK; ++j) {
      topk_idx[t * KK + j] = sel[j];
      wvec[t * KK + j] = sw[j] * s;
    }
  }
}

// ------ deterministic expert lists + compacted tile tables -------
// gu: BM=256 x BN=128; dn: BM=256 x BN=256
__global__ __launch_bounds__(1024)
void k_lists(const int* __restrict__ topk_idx,
             int* __restrict__ counts, int* __restrict__ offs,
             int* __restrict__ list, int* __restrict__ row_of,
             int* __restrict__ hdr, int* __restrict__ gu_tab,
             int* __restrict__ dn_tab)
{
  const int t = threadIdx.x;
  const int lane = t & 63, wv = t >> 6;
  const int e0 = topk_idx[t * 4 + 0], e1 = topk_idx[t * 4 + 1],
            e2 = topk_idx[t * 4 + 2], e3 = topk_idx[t * 4 + 3];
  __shared__ int wtot[16];
  __shared__ int cnt[EE];
  __shared__ int offsh[EE + 1];
  __shared__ int rtn[EE], gpre[EE + 1], dpre[EE + 1];
  int p0 = 0, p1 = 0, p2 = 0, p3 = 0;
  for (int e = 0; e < EE; ++e) {
    bool f = (e0 == e) || (e1 == e) || (e2 == e) || (e3 == e);
    unsigned long long b = __ballot(f);
    if (lane == 0) wtot[wv] = __popcll(b);
    __syncthreads();
    int wo = 0;
    for (int w2 = 0; w2 < wv; ++w2) wo += wtot[w2];
    if (f) {
      int pos = wo + __popcll(b & ((1ull << lane) - 1ull));
      list[e * TT + pos] = t;
      if (e0 == e) p0 = pos; else if (e1 == e) p1 = pos;
      else if (e2 == e) p2 = pos; else p3 = pos;
    }
    if (t == 0) {
      int tot = 0;
      for (int w2 = 0; w2 < 16; ++w2) tot += wtot[w2];
      cnt[e] = tot;
    }
    __syncthreads();
  }
  if (t == 0) {
    offsh[0] = 0;
    for (int e = 0; e < EE; ++e) offsh[e + 1] = offsh[e] + cnt[e];
    for (int e = 0; e < EE; ++e) { counts[e] = cnt[e]; offs[e] = offsh[e]; }
    gpre[0] = 0; dpre[0] = 0;
    for (int e = 0; e < EE; ++e) {
      int rr = (cnt[e] + 255) >> 8;           // ceil(cnt/256)
      rtn[e] = rr;
      gpre[e + 1] = gpre[e] + rr * (II / 128);
      dpre[e + 1] = dpre[e] + rr * (HH / 256);
    }
    hdr[0] = gpre[EE] + 4 * (IIS / 128);      // shared: 4 row-tiles of 256
    hdr[1] = dpre[EE] + 4 * (HH / 256);
  }
  __syncthreads();
  row_of[t * 4 + 0] = offsh[e0] + p0;
  row_of[t * 4 + 1] = offsh[e1] + p1;
  row_of[t * 4 + 2] = offsh[e2] + p2;
  row_of[t * 4 + 3] = offsh[e3] + p3;
  if (t < EE) {
    int rr = rtn[t];
    int p = gpre[t];
    for (int nt = 0; nt < II / 128; ++nt)
      for (int rt = 0; rt < rr; ++rt) gu_tab[p++] = (t << 16) | (rt << 8) | nt;
    p = dpre[t];
    for (int nt = 0; nt < HH / 256; ++nt)
      for (int rt = 0; rt < rr; ++rt) dn_tab[p++] = (t << 16) | (rt << 8) | nt;
  } else if (t == EE) {
    int p = gpre[EE];
    for (int nt = 0; nt < IIS / 128; ++nt)
      for (int rt = 0; rt < 4; ++rt) gu_tab[p++] = (EE << 16) | (rt << 8) | nt;
    p = dpre[EE];
    for (int nt = 0; nt < HH / 256; ++nt)
      for (int rt = 0; rt < 4; ++rt) dn_tab[p++] = (EE << 16) | (rt << 8) | nt;
  }
}

// ---- gate/up GEMM: BM=256 BN=128 BK=64, direct fp32 B, SINGLE reg-set ----
// acc = 128 AGPRs/thread -> arch-VGPR budget is 128; single R set (32 VGPR)
// + fragments (48) + addressing (~30) fits. 3-stage pipeline:
//   COMPUTE(b) | barrier | PACK R->Bs[b^1] | ISSUE R<-B(t+2), A(t+2)->As[b]
//   | lgkm0 + vmcnt(20) (drains A(t+1)) | barrier
__global__ __launch_bounds__(512)
void k_gu5(const __bf16* __restrict__ xb,
           const float* __restrict__ wg, const float* __restrict__ wu,
           const float* __restrict__ sg, const float* __restrict__ su,
           const int* __restrict__ counts, const int* __restrict__ offs,
           const int* __restrict__ list, const int* __restrict__ hdr,
           const int* __restrict__ gu_tab,
           __bf16* __restrict__ a_buf, __bf16* __restrict__ s_buf)
{
  const int nwg = hdr[0];
  const int orig = blockIdx.x;
  if (orig >= nwg) return;
  const int qq = nwg >> 3, r8 = nwg & 7, xcd = orig & 7;
  const int wgid = (xcd < r8 ? xcd * (qq + 1) : r8 * (qq + 1) + (xcd - r8) * qq)
                   + (orig >> 3);
  const int ent = gu_tab[wgid];
  const int e = ent >> 16, rt = (ent >> 8) & 255, nt = ent & 255;
  const bool SH = (e == EE);
  const int Nt = SH ? IIS : II;
  const int ldw = Nt;
  const int n0 = nt * 128, row0 = rt * 256;
  const int n_rows = SH ? TT : counts[e];
  if (row0 >= n_rows) return;
  const int base = SH ? 0 : offs[e];
  const float* Bg = SH ? sg : wg + (size_t)e * HH * II;   // [k][n] fp32
  const float* Bu = SH ? su : wu + (size_t)e * HH * II;
  __bf16* outp = SH ? s_buf : a_buf;

  __shared__ uint4 As[2][2048];    // 64KB
  __shared__ uint4 Bgs[2][1024];   // 32KB
  __shared__ uint4 Bus[2][1024];   // 32KB
  __shared__ int toks[256];

  const int tid = threadIdx.x;
  const int lane = tid & 63, w = tid >> 6;
  if (tid < 256) {
    int rr = row0 + tid;
    toks[tid] = SH ? rr : list[e * TT + (rr < n_rows ? rr : row0)];
  }
  __syncthreads();

  const __bf16* pA[4];
#pragma unroll
  for (int i = 0; i < 4; ++i) {
    int s = w * 256 + i * 64 + lane;
    int r = s >> 3, k8 = (s & 7) ^ (r & 7);
    pA[i] = xb + (size_t)toks[r] * HH + k8 * 8;
  }
  // B assignment: one (row-pair, k8) per thread per operand
  const int bq = lane;             // row-pair 0..63 -> rows 2bq, 2bq+1
  const int bk8 = w;               // k8 0..7
  const float* pBg = Bg + n0 + 2 * bq;
  const float* pBu = Bu + n0 + 2 * bq;
  const int bs0 = 16 * bq + (bk8 ^ (bq & 7));   // slot(2bq, bk8); +8 for row 2bq+1

  f32x4 accg[4][4], accu[4][4];
  const f32x4 fz = {0.f, 0.f, 0.f, 0.f};
#pragma unroll
  for (int m = 0; m < 4; ++m)
#pragma unroll
    for (int n = 0; n < 4; ++n) { accg[m][n] = fz; accu[m][n] = fz; }

  const int wm = w >> 1, wn = w & 1;
  const int lr = lane & 15, l16 = lane >> 4;
  const int NT = HH / 64;          // 32

  float2 Rg[8], Ru[8];             // SINGLE reg set: 32 VGPRs

  // Issue order: B loads (16) then A gl_lds (4) => wait vmcnt(4) covers B;
  // vmcnt(20) after a following 20-op issue covers this A group.
#define GU_ISSUE(ab, tt)                                                  \
  { const int kb_ = (tt) * 64;                                            \
    _Pragma("unroll") for (int j = 0; j < 8; ++j) {                       \
      Rg[j] = *reinterpret_cast<const float2*>(                           \
          pBg + (size_t)(kb_ + bk8 * 8 + j) * ldw);                       \
      Ru[j] = *reinterpret_cast<const float2*>(                           \
          pBu + (size_t)(kb_ + bk8 * 8 + j) * ldw);                       \
    }                                                                     \
    _Pragma("unroll") for (int i = 0; i < 4; ++i)                         \
      gl_lds16(pA[i] + kb_, &As[ab][w * 256 + i * 64]); }

#define GU_PACK(bb)                                                       \
  { uint4 q_;                                                             \
    q_.x = pk2(Rg[0].x, Rg[1].x); q_.y = pk2(Rg[2].x, Rg[3].x);           \
    q_.z = pk2(Rg[4].x, Rg[5].x); q_.w = pk2(Rg[6].x, Rg[7].x);           \
    Bgs[bb][bs0] = q_;                                                    \
    q_.x = pk2(Rg[0].y, Rg[1].y); q_.y = pk2(Rg[2].y, Rg[3].y);           \
    q_.z = pk2(Rg[4].y, Rg[5].y); q_.w = pk2(Rg[6].y, Rg[7].y);           \
    Bgs[bb][bs0 + 8] = q_;                                                \
    q_.x = pk2(Ru[0].x, Ru[1].x); q_.y = pk2(Ru[2].x, Ru[3].x);           \
    q_.z = pk2(Ru[4].x, Ru[5].x); q_.w = pk2(Ru[6].x, Ru[7].x);           \
    Bus[bb][bs0] = q_;                                                    \
    q_.x = pk2(Ru[0].y, Ru[1].y); q_.y = pk2(Ru[2].y, Ru[3].y);           \
    q_.z = pk2(Ru[4].y, Ru[5].y); q_.w = pk2(Ru[6].y, Ru[7].y);           \
    Bus[bb][bs0 + 8] = q_; }

#define GU_COMPUTE(bb)                                                    \
  { _Pragma("unroll") for (int ks = 0; ks < 2; ++ks) {                    \
      const int k8r = ks * 4 + l16;                                       \
      bf16x8 af[4], bg[4], bu[4];                                         \
      _Pragma("unroll") for (int m = 0; m < 4; ++m) {                     \
        int rw = wm * 64 + m * 16 + lr;                                   \
        af[m] = *reinterpret_cast<const bf16x8*>(                         \
            &As[bb][rw * 8 + (k8r ^ (rw & 7))]);                          \
      }                                                                   \
      _Pragma("unroll") for (int n = 0; n < 4; ++n) {                     \
        int cn = wn * 64 + n * 16 + lr;                                   \
        int sw_ = k8r ^ ((cn >> 1) & 7);                                  \
        bg[n] = *reinterpret_cast<const bf16x8*>(&Bgs[bb][cn * 8 + sw_]); \
        bu[n] = *reinterpret_cast<const bf16x8*>(&Bus[bb][cn * 8 + sw_]); \
      }                                                                   \
      _Pragma("unroll") for (int m = 0; m < 4; ++m)                       \
        _Pragma("unroll") for (int n = 0; n < 4; ++n) {                   \
          accg[m][n] = mfma16(af[m], bg[n], accg[m][n]);                  \
          accu[m][n] = mfma16(af[m], bu[n], accu[m][n]);                  \
        }                                                                 \
    } }

  // STEP(bb, tcur): R holds B(tcur+1); A(tcur+1) in flight to As[bb^1]
#define GU_STEP(bb, tcur)                                                 \
  { GU_COMPUTE(bb)                                                        \
    __builtin_amdgcn_s_barrier();                                         \
    if ((tcur) + 1 < NT) {                                                \
      GU_PACK((bb) ^ 1)                                                   \
      if ((tcur) + 2 < NT) {                                              \
        GU_ISSUE(bb, (tcur) + 2)                                          \
        asm volatile("s_waitcnt lgkmcnt(0)" ::: "memory");                \
        asm volatile("s_waitcnt vmcnt(20)" ::: "memory");                 \
      } else {                                                            \
        asm volatile("s_waitcnt lgkmcnt(0)" ::: "memory");                \
        asm volatile("s_waitcnt vmcnt(0)" ::: "memory");                  \
      }                                                                   \
      __builtin_amdgcn_s_barrier();                                       \
    } }

  // prologue: B(0)->R, A(0)->As[0]; pack B(0); B(1)->R, A(1)->As[1]
  GU_ISSUE(0, 0)
  GU_PACK(0)                        // compiler waits B(0) loads
  GU_ISSUE(1, 1)
  asm volatile("s_waitcnt lgkmcnt(0)" ::: "memory");
  asm volatile("s_waitcnt vmcnt(20)" ::: "memory");   // A(0) done (B1+A1=20 newer)
  __builtin_amdgcn_s_barrier();

  for (int t = 0; t < NT; t += 2) {
    GU_STEP(0, t)
    GU_STEP(1, t + 1)
  }

#pragma unroll
  for (int m = 0; m < 4; ++m)
#pragma unroll
    for (int n = 0; n < 4; ++n)
#pragma unroll
      for (int q = 0; q < 4; ++q) {
        int rloc = wm * 64 + m * 16 + l16 * 4 + q;
        if (row0 + rloc >= n_rows) continue;
        int cloc = wn * 64 + n * 16 + lr;
        float g = accg[m][n][q], u = accu[m][n][q];
        float sv = g / (1.f + __expf(-g)) * u;
        outp[(size_t)(base + row0 + rloc) * Nt + (n0 + cloc)] = (__bf16)sv;
      }
#undef GU_ISSUE
#undef GU_PACK
#undef GU_COMPUTE
#undef GU_STEP
}

// ---- down GEMM: BM=256 BN=256 BK=64, direct fp32 B, SINGLE reg-set ----
__global__ __launch_bounds__(512)
void k_down6(const __bf16* __restrict__ a_buf, const __bf16* __restrict__ s_buf,
             const float* __restrict__ wd, const float* __restrict__ sd,
             const int* __restrict__ counts, const int* __restrict__ offs,
             const int* __restrict__ hdr, const int* __restrict__ dn_tab,
             __bf16* __restrict__ eo, float* __restrict__ out)
{
  const int nwg = hdr[1];
  const int orig = blockIdx.x;
  if (orig >= nwg) return;
  const int qq = nwg >> 3, r8 = nwg & 7, xcd = orig & 7;
  const int wgid = (xcd < r8 ? xcd * (qq + 1) : r8 * (qq + 1) + (xcd - r8) * qq)
                   + (orig >> 3);
  const int ent = dn_tab[wgid];
  const int e = ent >> 16, rt = (ent >> 8) & 255, nt = ent & 255;
  const bool SH = (e == EE);
  const int Kdim = SH ? IIS : II;
  const int n_rows = SH ? TT : counts[e];
  const int row0 = rt * 256, n0 = nt * 256;
  if (row0 >= n_rows) return;
  const int base = SH ? 0 : offs[e];
  const __bf16* Ain = SH ? s_buf : a_buf + (size_t)base * II;
  const float* Bd = SH ? sd : wd + (size_t)e * (size_t)II * HH;  // [k][n], ld HH

  __shared__ uint4 As[2][2048];   // 64KB
  __shared__ uint4 Bs[2][2048];   // 64KB

  const int tid = threadIdx.x;
  const int lane = tid & 63, w = tid >> 6;
  const int wm = w >> 2, wn = w & 3;
  const int lr = lane & 15, l16 = lane >> 4;

  const __bf16* pA[4];
#pragma unroll
  for (int i = 0; i < 4; ++i) {
    int s = w * 256 + i * 64 + lane;
    int r = s >> 3, k8 = (s & 7) ^ (r & 7);
    int rr = row0 + r; if (rr >= n_rows) rr = row0;
    pA[i] = Ain + (size_t)rr * Kdim + k8 * 8;
  }
  const int dq = (w & 1) * 64 + lane;   // row-pair 0..127 -> rows 2dq,2dq+1
  const int dk0 = (w >> 1) * 2;         // k8 in {dk0, dk0+1}
  const float* pBd = Bd + n0 + 2 * dq;
  const int ds0 = 16 * dq + (dk0 ^ (dq & 7));        // slot(2dq, dk0)
  const int ds1 = 16 * dq + ((dk0 + 1) ^ (dq & 7));  // slot(2dq, dk0+1)

  f32x4 acc[8][4];
  const f32x4 fz = {0.f, 0.f, 0.f, 0.f};
#pragma unroll
  for (int m = 0; m < 8; ++m)
#pragma unroll
    for (int n = 0; n < 4; ++n) acc[m][n] = fz;

  const int NTS = Kdim >> 6;  // 22 or 44 (even)
  float2 Rd[16];              // SINGLE reg set: 32 VGPRs

#define DN_ISSUE(ab, tt)                                                  \
  { const int kb_ = (tt) * 64;                                            \
    _Pragma("unroll") for (int j = 0; j < 8; ++j) {                       \
      Rd[j] = *reinterpret_cast<const float2*>(                           \
          pBd + (size_t)(kb_ + dk0 * 8 + j) * HH);                        \
      Rd[8 + j] = *reinterpret_cast<const float2*>(                       \
          pBd + (size_t)(kb_ + (dk0 + 1) * 8 + j) * HH);                  \
    }                                                                     \
    _Pragma("unroll") for (int i = 0; i < 4; ++i)                         \
      gl_lds16(pA[i] + kb_, &As[ab][w * 256 + i * 64]); }

#define DN_PACK(bb)                                                       \
  { uint4 q_;                                                             \
    q_.x = pk2(Rd[0].x, Rd[1].x); q_.y = pk2(Rd[2].x, Rd[3].x);           \
    q_.z = pk2(Rd[4].x, Rd[5].x); q_.w = pk2(Rd[6].x, Rd[7].x);           \
    Bs[bb][ds0] = q_;                                                     \
    q_.x = pk2(Rd[0].y, Rd[1].y); q_.y = pk2(Rd[2].y, Rd[3].y);           \
    q_.z = pk2(Rd[4].y, Rd[5].y); q_.w = pk2(Rd[6].y, Rd[7].y);           \
    Bs[bb][ds0 + 8] = q_;                                                 \
    q_.x = pk2(Rd[8].x, Rd[9].x); q_.y = pk2(Rd[10].x, Rd[11].x);         \
    q_.z = pk2(Rd[12].x, Rd[13].x); q_.w = pk2(Rd[14].x, Rd[15].x);       \
    Bs[bb][ds1] = q_;                                                     \
    q_.x = pk2(Rd[8].y, Rd[9].y); q_.y = pk2(Rd[10].y, Rd[11].y);         \
    q_.z = pk2(Rd[12].y, Rd[13].y); q_.w = pk2(Rd[14].y, Rd[15].y);       \
    Bs[bb][ds1 + 8] = q_; }

#define DN_COMPUTE(bb)                                                    \
  { _Pragma("unroll") for (int ks = 0; ks < 2; ++ks) {                    \
      const int k8r = ks * 4 + l16;                                       \
      bf16x8 af[8], bb_[4];                                               \
      _Pragma("unroll") for (int m = 0; m < 8; ++m) {                     \
        int rw = wm * 128 + m * 16 + lr;                                  \
        af[m] = *reinterpret_cast<const bf16x8*>(                         \
            &As[bb][rw * 8 + (k8r ^ (rw & 7))]);                          \
      }                                                                   \
      _Pragma("unroll") for (int n = 0; n < 4; ++n) {                     \
        int cn = wn * 64 + n * 16 + lr;                                   \
        bb_[n] = *reinterpret_cast<const bf16x8*>(                        \
            &Bs[bb][cn * 8 + (k8r ^ ((cn >> 1) & 7))]);                   \
      }                                                                   \
      _Pragma("unroll") for (int m = 0; m < 8; ++m)                       \
        _Pragma("unroll") for (int n = 0; n < 4; ++n)                     \
          acc[m][n] = mfma16(af[m], bb_[n], acc[m][n]);                   \
    } }

#define DN_STEP(bb, tcur)                                                 \
  { DN_COMPUTE(bb)                                                        \
    __builtin_amdgcn_s_barrier();                                         \
    if ((tcur) + 1 < NTS) {                                               \
      DN_PACK((bb) ^ 1)                                                   \
      if ((tcur) + 2 < NTS) {                                             \
        DN_ISSUE(bb, (tcur) + 2)                                          \
        asm volatile("s_waitcnt lgkmcnt(0)" ::: "memory");                \
        asm volatile("s_waitcnt vmcnt(20)" ::: "memory");                 \
      } else {                                                            \
        asm volatile("s_waitcnt lgkmcnt(0)" ::: "memory");                \
        asm volatile("s_waitcnt vmcnt(0)" ::: "memory");                  \
      }                                                                   \
      __builtin_amdgcn_s_barrier();                                       \
    } }

  // prologue
  DN_ISSUE(0, 0)
  DN_PACK(0)
  DN_ISSUE(1, 1)
  asm volatile("s_waitcnt lgkmcnt(0)" ::: "memory");
  asm volatile("s_waitcnt vmcnt(20)" ::: "memory");
  __builtin_amdgcn_s_barrier();

  for (int t = 0; t < NTS; t += 2) {
    DN_STEP(0, t)
    DN_STEP(1, t + 1)
  }

#pragma unroll
  for (int m = 0; m < 8; ++m)
#pragma unroll
    for (int n = 0; n < 4; ++n)
#pragma unroll
      for (int q = 0; q < 4; ++q) {
        int rloc = wm * 128 + m * 16 + l16 * 4 + q;
        int cloc = wn * 64 + n * 16 + lr;
        if (SH) {
          out[(size_t)(row0 + rloc) * HH + (n0 + cloc)] = acc[m][n][q];
        } else if (row0 + rloc < n_rows) {
          eo[(size_t)(base + row0 + rloc) * HH + (n0 + cloc)] = (__bf16)acc[m][n][q];
        }
      }
#undef DN_ISSUE
#undef DN_PACK
#undef DN_COMPUTE
#undef DN_STEP
}

// ------------- weighted combine: out += sum_j w_j * eo[row_j] -------------
__global__ __launch_bounds__(256)
void k_combine(const __bf16* __restrict__ eo, const int* __restrict__ row_of,
               const float* __restrict__ wvec, float* __restrict__ out)
{
  const int t = blockIdx.x, tid = threadIdx.x;
  const int h0 = tid * 8;
  float acc[8];
  float4* op = reinterpret_cast<float4*>(out + (size_t)t * HH + h0);
  float4 o0 = op[0], o1 = op[1];
  acc[0] = o0.x; acc[1] = o0.y; acc[2] = o0.z; acc[3] = o0.w;
  acc[4] = o1.x; acc[5] = o1.y; acc[6] = o1.z; acc[7] = o1.w;
#pragma unroll
  for (int j = 0; j < 4; ++j) {
    int r = row_of[t * 4 + j];
    float wj = wvec[t * 4 + j];
    uint4 v = *reinterpret_cast<const uint4*>(eo + (size_t)r * HH + h0);
    unsigned int ws4[4] = {v.x, v.y, v.z, v.w};
#pragma unroll
    for (int q = 0; q < 4; ++q) {
      acc[q * 2 + 0] += wj * bf2f((unsigned short)(ws4[q] & 0xffffu));
      acc[q * 2 + 1] += wj * bf2f((unsigned short)(ws4[q] >> 16));
    }
  }
  o0.x = acc[0]; o0.y = acc[1]; o0.z = acc[2]; o0.w = acc[3];
  o1.x = acc[4]; o1.y = acc[5]; o1.z = acc[6]; o1.w = acc[7];
  op[0] = o0; op[1] = o1;
}

extern "C" void kernel_launch(void* const* d_in, const int* in_sizes, int n_in,
                              void* d_out, int out_size, void* d_ws, size_t ws_size,
                              hipStream_t stream) {
  const float* x  = (const float*)d_in[0];
  const float* gw = (const float*)d_in[1];
  const float* gb = (const float*)d_in[2];
  const float* wg = (const float*)d_in[3];
  const float* wu = (const float*)d_in[4];
  const float* wd = (const float*)d_in[5];
  const float* sg = (const float*)d_in[6];
  const float* su = (const float*)d_in[7];
  const float* sd = (const float*)d_in[8];
  float* out = (float*)d_out;

  char* ws = (char*)d_ws;
  size_t off = 0;
  auto carve = [&](size_t bytes) {
    off = (off + 255) & ~(size_t)255;
    void* p = (void*)(ws + off);
    off += bytes;
    return p;
  };
  int*    topk_idx = (int*)carve((size_t)TT * KK * 4);
  float*  wvec     = (float*)carve((size_t)TT * KK * 4);
  int*    counts   = (int*)carve(EE * 4);
  int*    offs     = (int*)carve(EE * 4);
  int*    list     = (int*)carve((size_t)EE * TT * 4);
  int*    row_of   = (int*)carve((size_t)TT * KK * 4);
  int*    hdr      = (int*)carve(64);
  int*    gu_tab   = (int*)carve(GU_MAXT * 4);
  int*    dn_tab   = (int*)carve(DN_MAXT * 4);
  __bf16* xb       = (__bf16*)carve((size_t)TT * HH * 2);
  __bf16* a_buf    = (__bf16*)carve((size_t)TT * KK * II * 2);
  __bf16* s_buf    = (__bf16*)carve((size_t)TT * IIS * 2);
  __bf16* eo       = (__bf16*)carve((size_t)TT * KK * HH * 2);
  (void)ws_size;  // ~38 MB needed, well under provided workspace

  k_route<<<TT, 256, 0, stream>>>(x, gw, gb, topk_idx, wvec, xb);
  k_lists<<<1, 1024, 0, stream>>>(topk_idx, counts, offs, list, row_of,
                                  hdr, gu_tab, dn_tab);
  // gate/up GEMM: direct fp32 weights, on-the-fly convert+transpose in LDS
  k_gu5<<<GU_MAXT, 512, 0, stream>>>(
      xb, wg, wu, sg, su, counts, offs, list, hdr, gu_tab, a_buf, s_buf);
  // down GEMM: direct fp32 weights (routed -> eo, shared -> out)
  k_down6<<<DN_MAXT, 512, 0, stream>>>(
      a_buf, s_buf, wd, sd, counts, offs, hdr, dn_tab, eo, out);
  k_combine<<<TT, 256, 0, stream>>>(eo, row_of, wvec, out);
}

// Round 13
// 401.798 us; speedup vs baseline: 4.0477x; 2.9663x over previous
//
#include <hip/hip_runtime.h>
#include <hip/hip_bf16.h>

#define TT 1024
#define HH 2048
#define EE 16
#define KK 4
#define II 1408
#define IIS 2816
#define GU_MAXT 448
#define DN_MAXT 288
#define TRD_WD (32 * 22 * 16)   // wd transpose tiles
#define TRD_SD (32 * 44)        // sd transpose tiles
#define TRD_BLK ((TRD_WD + TRD_SD) / 4)
// route+tr fused dispatch tile counts
#define TR_GU (22 * 32 * 32)    // wg+wu tiles
#define TR_SGU (44 * 32 * 2)    // sg+su tiles

typedef __bf16 bf16x8 __attribute__((ext_vector_type(8)));
typedef float f32x4 __attribute__((ext_vector_type(4)));

__device__ __forceinline__ f32x4 mfma16(bf16x8 a, bf16x8 b, f32x4 c) {
  return __builtin_amdgcn_mfma_f32_16x16x32_bf16(a, b, c, 0, 0, 0);
}

__device__ __forceinline__ void gl_lds16(const void* g, void* l) {
  __builtin_amdgcn_global_load_lds(
      (const __attribute__((address_space(1))) void*)g,
      (__attribute__((address_space(3))) void*)l, 16, 0, 0);
}

__device__ __forceinline__ unsigned int pk2(float a, float b) {
  unsigned short lo = __builtin_bit_cast(unsigned short, (__bf16)a);
  unsigned short hi = __builtin_bit_cast(unsigned short, (__bf16)b);
  return (unsigned int)lo | ((unsigned int)hi << 16);
}

__device__ __forceinline__ uint4 pack8(const float* f) {
  uint4 r;
  r.x = pk2(f[0], f[1]);
  r.y = pk2(f[2], f[3]);
  r.z = pk2(f[4], f[5]);
  r.w = pk2(f[6], f[7]);
  return r;
}

__device__ __forceinline__ float bf2f(unsigned short u) {
  return __builtin_bit_cast(float, (unsigned int)u << 16);
}

// ------------- transpose tile bodies: [R][C] fp32 -> [C][R] bf16 -------------
__device__ __forceinline__ void tr_body(const float* __restrict__ src,
                                        __bf16* __restrict__ dst,
                                        const int R, const int C,
                                        const int xb, const int yb, const int zb,
                                        float (*t)[65])
{
  const int tid = threadIdx.x;
  const size_t mb = (size_t)zb * R * C;
  const int r0 = yb * 64, c0 = xb * 64;
#pragma unroll
  for (int it = 0; it < 4; ++it) {
    int idx = it * 256 + tid;
    int r = idx >> 4, q = idx & 15;
    float4 v = *reinterpret_cast<const float4*>(
        src + mb + (size_t)(r0 + r) * C + c0 + q * 4);
    t[r][q * 4 + 0] = v.x; t[r][q * 4 + 1] = v.y;
    t[r][q * 4 + 2] = v.z; t[r][q * 4 + 3] = v.w;
  }
  __syncthreads();
#pragma unroll
  for (int it = 0; it < 2; ++it) {
    int idx = it * 256 + tid;
    int n = idx >> 3, q8 = idx & 7;
    float f[8];
#pragma unroll
    for (int j = 0; j < 8; ++j) f[j] = t[q8 * 8 + j][n];
    *reinterpret_cast<uint4*>(dst + mb + (size_t)(c0 + n) * R + r0 + q8 * 8) = pack8(f);
  }
}

__device__ __forceinline__ void tr_body512(const float* __restrict__ src,
                                           __bf16* __restrict__ dst,
                                           const int R, const int C,
                                           const int xb, const int yb, const int zb,
                                           float (*t)[65])
{
  const int tid = threadIdx.x;   // 0..511
  const size_t mb = (size_t)zb * R * C;
  const int r0 = yb * 64, c0 = xb * 64;
#pragma unroll
  for (int it = 0; it < 2; ++it) {
    int idx = it * 512 + tid;
    int r = idx >> 4, q = idx & 15;
    float4 v = *reinterpret_cast<const float4*>(
        src + mb + (size_t)(r0 + r) * C + c0 + q * 4);
    t[r][q * 4 + 0] = v.x; t[r][q * 4 + 1] = v.y;
    t[r][q * 4 + 2] = v.z; t[r][q * 4 + 3] = v.w;
  }
  __syncthreads();
  {
    int n = tid >> 3, q8 = tid & 7;
    float f[8];
#pragma unroll
    for (int j = 0; j < 8; ++j) f[j] = t[q8 * 8 + j][n];
    *reinterpret_cast<uint4*>(dst + mb + (size_t)(c0 + n) * R + r0 + q8 * 8) = pack8(f);
  }
}

// ------- fused: routing (blocks < TT) + gate/up/shared-gu weight transpose ---
__global__ __launch_bounds__(256)
void k_route_tr(const float* __restrict__ x, const float* __restrict__ gw,
                const float* __restrict__ gb,
                int* __restrict__ topk_idx, float* __restrict__ wvec,
                __bf16* __restrict__ xb,
                const float* __restrict__ wg, __bf16* __restrict__ wgT,
                const float* __restrict__ wu, __bf16* __restrict__ wuT,
                const float* __restrict__ sg, __bf16* __restrict__ sgT,
                const float* __restrict__ su, __bf16* __restrict__ suT)
{
  __shared__ float tsm[64][65];
  const int bid = blockIdx.x;
  const int tid = threadIdx.x;
  if (bid >= TT) {
    int tb = bid - TT;
    if (tb < TR_GU) {
      int xb_ = tb % 22, yb_ = (tb / 22) & 31, z = tb / (22 * 32);
      if (z < EE) tr_body(wg, wgT, HH, II, xb_, yb_, z, tsm);
      else        tr_body(wu, wuT, HH, II, xb_, yb_, z - EE, tsm);
    } else {
      int t2 = tb - TR_GU;
      int xb_ = t2 % 44, yb_ = (t2 / 44) & 31, z = t2 / (44 * 32);
      if (z == 0) tr_body(sg, sgT, HH, IIS, xb_, yb_, 0, tsm);
      else        tr_body(su, suT, HH, IIS, xb_, yb_, 0, tsm);
    }
    return;
  }
  // ---------------- routing body ----------------
  const int t = bid;
  float a[EE];
#pragma unroll
  for (int e = 0; e < EE; ++e) a[e] = 0.f;
  for (int h = tid; h < HH; h += 256) {
    float xv = x[(size_t)t * HH + h];
    xb[(size_t)t * HH + h] = (__bf16)xv;
#pragma unroll
    for (int e = 0; e < EE; ++e) a[e] += xv * gw[e * HH + h];
  }
  const int lane = tid & 63, wv = tid >> 6;
#pragma unroll
  for (int e = 0; e < EE; ++e) {
    float v = a[e];
#pragma unroll
    for (int off = 32; off > 0; off >>= 1) v += __shfl_xor(v, off);
    if (lane == 0) tsm[wv][e] = v;
  }
  __syncthreads();
  if (tid == 0) {
    float sc[EE], sb[EE];
    for (int e = 0; e < EE; ++e) {
      float lg = tsm[0][e] + tsm[1][e] + tsm[2][e] + tsm[3][e];
      sc[e] = 1.f / (1.f + expf(-lg));
      sb[e] = sc[e] + gb[e];
    }
    float gsc[4];
    for (int g = 0; g < 4; ++g) {
      float m1 = -1e30f, m2 = -1e30f;
      for (int j = 0; j < 4; ++j) {
        float v = sb[g * 4 + j];
        if (v > m1) { m2 = m1; m1 = v; } else if (v > m2) { m2 = v; }
      }
      gsc[g] = m1 + m2;
    }
    int g1 = 0; float b1 = gsc[0];
    for (int g = 1; g < 4; ++g) if (gsc[g] > b1) { b1 = gsc[g]; g1 = g; }
    int g2 = 0; float b2 = -1e30f;
    for (int g = 0; g < 4; ++g) if (g != g1 && gsc[g] > b2) { b2 = gsc[g]; g2 = g; }
    bool used[EE];
    for (int e = 0; e < EE; ++e) used[e] = !(((e >> 2) == g1) || ((e >> 2) == g2));
    int sel[KK]; float sw[KK]; float ssum = 0.f;
    for (int j = 0; j < KK; ++j) {
      float best = -1e30f; int bi = 0;
      for (int e = 0; e < EE; ++e)
        if (!used[e] && sb[e] > best) { best = sb[e]; bi = e; }
      used[bi] = true; sel[j] = bi; sw[j] = sc[bi]; ssum += sc[bi];
    }
    float s = 2.5f / (ssum + 1e-20f);
    for (int j = 0; j < KK; ++j) {
      topk_idx[t * KK + j] = sel[j];
      wvec[t * KK + j] = sw[j] * s;
    }
  }
}

// ------ deterministic expert lists + compacted tile tables -------
// gu: BM=256 x BN=128; dn: BM=256 x BN=256
__global__ __launch_bounds__(1024)
void k_lists(const int* __restrict__ topk_idx,
             int* __restrict__ counts, int* __restrict__ offs,
             int* __restrict__ list, int* __restrict__ row_of,
             int* __restrict__ hdr, int* __restrict__ gu_tab,
             int* __restrict__ dn_tab)
{
  const int t = threadIdx.x;
  const int lane = t & 63, wv = t >> 6;
  const int e0 = topk_idx[t * 4 + 0], e1 = topk_idx[t * 4 + 1],
            e2 = topk_idx[t * 4 + 2], e3 = topk_idx[t * 4 + 3];
  __shared__ int wtot[16];
  __shared__ int cnt[EE];
  __shared__ int offsh[EE + 1];
  __shared__ int rtn[EE], gpre[EE + 1], dpre[EE + 1];
  int p0 = 0, p1 = 0, p2 = 0, p3 = 0;
  for (int e = 0; e < EE; ++e) {
    bool f = (e0 == e) || (e1 == e) || (e2 == e) || (e3 == e);
    unsigned long long b = __ballot(f);
    if (lane == 0) wtot[wv] = __popcll(b);
    __syncthreads();
    int wo = 0;
    for (int w2 = 0; w2 < wv; ++w2) wo += wtot[w2];
    if (f) {
      int pos = wo + __popcll(b & ((1ull << lane) - 1ull));
      list[e * TT + pos] = t;
      if (e0 == e) p0 = pos; else if (e1 == e) p1 = pos;
      else if (e2 == e) p2 = pos; else p3 = pos;
    }
    if (t == 0) {
      int tot = 0;
      for (int w2 = 0; w2 < 16; ++w2) tot += wtot[w2];
      cnt[e] = tot;
    }
    __syncthreads();
  }
  if (t == 0) {
    offsh[0] = 0;
    for (int e = 0; e < EE; ++e) offsh[e + 1] = offsh[e] + cnt[e];
    for (int e = 0; e < EE; ++e) { counts[e] = cnt[e]; offs[e] = offsh[e]; }
    gpre[0] = 0; dpre[0] = 0;
    for (int e = 0; e < EE; ++e) {
      int rr = (cnt[e] + 255) >> 8;           // ceil(cnt/256)
      rtn[e] = rr;
      gpre[e + 1] = gpre[e] + rr * (II / 128);
      dpre[e + 1] = dpre[e] + rr * (HH / 256);
    }
    hdr[0] = gpre[EE] + 4 * (IIS / 128);      // shared: 4 row-tiles of 256
    hdr[1] = dpre[EE] + 4 * (HH / 256);
  }
  __syncthreads();
  row_of[t * 4 + 0] = offsh[e0] + p0;
  row_of[t * 4 + 1] = offsh[e1] + p1;
  row_of[t * 4 + 2] = offsh[e2] + p2;
  row_of[t * 4 + 3] = offsh[e3] + p3;
  if (t < EE) {
    int rr = rtn[t];
    int p = gpre[t];
    for (int nt = 0; nt < II / 128; ++nt)
      for (int rt = 0; rt < rr; ++rt) gu_tab[p++] = (t << 16) | (rt << 8) | nt;
    p = dpre[t];
    for (int nt = 0; nt < HH / 256; ++nt)
      for (int rt = 0; rt < rr; ++rt) dn_tab[p++] = (t << 16) | (rt << 8) | nt;
  } else if (t == EE) {
    int p = gpre[EE];
    for (int nt = 0; nt < IIS / 128; ++nt)
      for (int rt = 0; rt < 4; ++rt) gu_tab[p++] = (EE << 16) | (rt << 8) | nt;
    p = dpre[EE];
    for (int nt = 0; nt < HH / 256; ++nt)
      for (int rt = 0; rt < 4; ++rt) dn_tab[p++] = (EE << 16) | (rt << 8) | nt;
  }
}

// ---- fused: gate/up GEMM (BM=256, dbuf, counted-vmcnt) + wd/sd transpose ----
struct GU_SM {
  uint4 As[2][2048];
  uint4 Bgs[2][1024];
  uint4 Bus[2][1024];
  int toks[256];
};
union FSM { GU_SM g; float t[64][65]; };

__global__ __launch_bounds__(512)
void k_gu_trd(const __bf16* __restrict__ xb,
              const __bf16* __restrict__ wgT, const __bf16* __restrict__ wuT,
              const __bf16* __restrict__ sgT, const __bf16* __restrict__ suT,
              const int* __restrict__ counts, const int* __restrict__ offs,
              const int* __restrict__ list, const int* __restrict__ hdr,
              const int* __restrict__ gu_tab,
              __bf16* __restrict__ a_buf, __bf16* __restrict__ s_buf,
              const float* __restrict__ wd, __bf16* __restrict__ wdT,
              const float* __restrict__ sd, __bf16* __restrict__ sdT)
{
  __shared__ FSM sm;
  const int bid = blockIdx.x;
  if (bid >= GU_MAXT) {
    const int tb = bid - GU_MAXT;
#pragma unroll
    for (int j = 0; j < 4; ++j) {
      if (j) __syncthreads();
      int tile = tb * 4 + j;
      if (tile < TRD_WD) {
        int xb_ = tile & 31, yb_ = (tile >> 5) % 22, zb_ = tile / (32 * 22);
        tr_body512(wd, wdT, II, HH, xb_, yb_, zb_, sm.t);
      } else {
        int t2 = tile - TRD_WD;
        int xb_ = t2 & 31, yb_ = t2 >> 5;
        tr_body512(sd, sdT, IIS, HH, xb_, yb_, 0, sm.t);
      }
    }
    return;
  }
  const int nwg = hdr[0];
  if (bid >= nwg) return;
  const int qq = nwg >> 3, r8 = nwg & 7, xcd = bid & 7;
  const int wgid = (xcd < r8 ? xcd * (qq + 1) : r8 * (qq + 1) + (xcd - r8) * qq)
                   + (bid >> 3);
  const int ent = gu_tab[wgid];
  const int e = ent >> 16, rt = (ent >> 8) & 255, nt = ent & 255;
  const bool SH = (e == EE);
  const int Nt = SH ? IIS : II;
  const int n0 = nt * 128, row0 = rt * 256;
  const int n_rows = SH ? TT : counts[e];
  if (row0 >= n_rows) return;
  const int base = SH ? 0 : offs[e];
  const __bf16* Bg = SH ? sgT : wgT + (size_t)e * II * HH;
  const __bf16* Bu = SH ? suT : wuT + (size_t)e * II * HH;
  __bf16* outp = SH ? s_buf : a_buf;

  const int tid = threadIdx.x;
  const int lane = tid & 63, w = tid >> 6;
  if (tid < 256) {
    int rr = row0 + tid;
    sm.g.toks[tid] = SH ? rr : list[e * TT + (rr < n_rows ? rr : row0)];
  }
  __syncthreads();

  const __bf16 *pA[4], *pBg[2], *pBu[2];
#pragma unroll
  for (int i = 0; i < 4; ++i) {
    int s = w * 256 + i * 64 + lane;
    int r = s >> 3, k8 = (s & 7) ^ (r & 7);
    pA[i] = xb + (size_t)sm.g.toks[r] * HH + k8 * 8;
  }
#pragma unroll
  for (int i = 0; i < 2; ++i) {
    int s = w * 128 + i * 64 + lane;
    int r = s >> 3, k8 = (s & 7) ^ (r & 7);
    pBg[i] = Bg + (size_t)(n0 + r) * HH + k8 * 8;
    pBu[i] = Bu + (size_t)(n0 + r) * HH + k8 * 8;
  }

  f32x4 accg[4][4], accu[4][4];
  const f32x4 fz = {0.f, 0.f, 0.f, 0.f};
#pragma unroll
  for (int m = 0; m < 4; ++m)
#pragma unroll
    for (int n = 0; n < 4; ++n) { accg[m][n] = fz; accu[m][n] = fz; }

  const int wm = w >> 1, wn = w & 1;
  const int lr = lane & 15, l16 = lane >> 4;

#define GU_STAGE(b, k0)                                            \
  {                                                                \
    _Pragma("unroll")                                              \
    for (int i = 0; i < 4; ++i)                                    \
      gl_lds16(pA[i] + (k0), &sm.g.As[b][w * 256 + i * 64]);       \
    _Pragma("unroll")                                              \
    for (int i = 0; i < 2; ++i) {                                  \
      gl_lds16(pBg[i] + (k0), &sm.g.Bgs[b][w * 128 + i * 64]);     \
      gl_lds16(pBu[i] + (k0), &sm.g.Bus[b][w * 128 + i * 64]);     \
    }                                                              \
  }

  GU_STAGE(0, 0);
  int cur = 0;
  for (int t = 0; t < HH / 64; ++t) {
    if (t + 1 < HH / 64) {
      GU_STAGE(cur ^ 1, (t + 1) * 64);
      asm volatile("s_waitcnt vmcnt(8)" ::: "memory");
    } else {
      asm volatile("s_waitcnt vmcnt(0)" ::: "memory");
    }
    __builtin_amdgcn_s_barrier();
#pragma unroll
    for (int ks = 0; ks < 2; ++ks) {
      const int k8r = ks * 4 + l16;
      bf16x8 af[4], bg[4], bu[4];
#pragma unroll
      for (int m = 0; m < 4; ++m) {
        int rw = wm * 64 + m * 16 + lr;
        af[m] = *reinterpret_cast<const bf16x8*>(
            &sm.g.As[cur][rw * 8 + (k8r ^ (rw & 7))]);
      }
#pragma unroll
      for (int n = 0; n < 4; ++n) {
        int cn = wn * 64 + n * 16 + lr;
        bg[n] = *reinterpret_cast<const bf16x8*>(
            &sm.g.Bgs[cur][cn * 8 + (k8r ^ (cn & 7))]);
        bu[n] = *reinterpret_cast<const bf16x8*>(
            &sm.g.Bus[cur][cn * 8 + (k8r ^ (cn & 7))]);
      }
#pragma unroll
      for (int m = 0; m < 4; ++m)
#pragma unroll
        for (int n = 0; n < 4; ++n) {
          accg[m][n] = mfma16(af[m], bg[n], accg[m][n]);
          accu[m][n] = mfma16(af[m], bu[n], accu[m][n]);
        }
    }
    __builtin_amdgcn_s_barrier();
    cur ^= 1;
  }
#pragma unroll
  for (int m = 0; m < 4; ++m)
#pragma unroll
    for (int n = 0; n < 4; ++n)
#pragma unroll
      for (int q = 0; q < 4; ++q) {
        int rloc = wm * 64 + m * 16 + l16 * 4 + q;
        if (row0 + rloc >= n_rows) continue;
        int cloc = wn * 64 + n * 16 + lr;
        float g = accg[m][n][q], u = accu[m][n][q];
        float sv = g / (1.f + __expf(-g)) * u;
        outp[(size_t)(base + row0 + rloc) * Nt + (n0 + cloc)] = (__bf16)sv;
      }
#undef GU_STAGE
}

// ---- down GEMM: BM=256, BN=256, BK=64, 8 waves (2x4), counted-vmcnt ----
__global__ __launch_bounds__(512)
void k_down5(const __bf16* __restrict__ a_buf, const __bf16* __restrict__ s_buf,
             const __bf16* __restrict__ wdT, const __bf16* __restrict__ sdT,
             const int* __restrict__ counts, const int* __restrict__ offs,
             const int* __restrict__ hdr, const int* __restrict__ dn_tab,
             __bf16* __restrict__ eo, float* __restrict__ out)
{
  const int nwg = hdr[1];
  const int orig = blockIdx.x;
  if (orig >= nwg) return;
  const int qq = nwg >> 3, r8 = nwg & 7, xcd = orig & 7;
  const int wgid = (xcd < r8 ? xcd * (qq + 1) : r8 * (qq + 1) + (xcd - r8) * qq)
                   + (orig >> 3);
  const int ent = dn_tab[wgid];
  const int e = ent >> 16, rt = (ent >> 8) & 255, nt = ent & 255;
  const bool SH = (e == EE);
  const int Kdim = SH ? IIS : II;
  const int n_rows = SH ? TT : counts[e];
  const int row0 = rt * 256, n0 = nt * 256;
  if (row0 >= n_rows) return;
  const int base = SH ? 0 : offs[e];
  const __bf16* Ain = SH ? s_buf : a_buf + (size_t)base * II;
  const __bf16* Bd = SH ? sdT : wdT + (size_t)e * HH * II;

  __shared__ uint4 As[2][2048];    // 256 rows x 8 slots
  __shared__ uint4 Bs[2][2048];    // 256 cols x 8 slots

  const int tid = threadIdx.x;
  const int lane = tid & 63, w = tid >> 6;
  const int wm = w >> 2, wn = w & 3;           // 2x4: per-wave 128 rows x 64 cols
  const int lr = lane & 15, l16 = lane >> 4;

  const __bf16 *pA[4], *pB[4];
#pragma unroll
  for (int i = 0; i < 4; ++i) {
    int s = w * 256 + i * 64 + lane;
    int r = s >> 3, k8 = (s & 7) ^ (r & 7);
    int rr = row0 + r; if (rr >= n_rows) rr = row0;
    pA[i] = Ain + (size_t)rr * Kdim + k8 * 8;
    pB[i] = Bd + (size_t)(n0 + r) * Kdim + k8 * 8;
  }

  f32x4 acc[8][4];
  const f32x4 fz = {0.f, 0.f, 0.f, 0.f};
#pragma unroll
  for (int m = 0; m < 8; ++m)
#pragma unroll
    for (int n = 0; n < 4; ++n) acc[m][n] = fz;

#define DN_STAGE(b, k0)                                           \
  {                                                               \
    _Pragma("unroll")                                             \
    for (int i = 0; i < 4; ++i) {                                 \
      gl_lds16(pA[i] + (k0), &As[b][w * 256 + i * 64]);           \
      gl_lds16(pB[i] + (k0), &Bs[b][w * 256 + i * 64]);           \
    }                                                             \
  }

  const int NTS = Kdim >> 6;
  DN_STAGE(0, 0);
  int cur = 0;
  for (int t = 0; t < NTS; ++t) {
    if (t + 1 < NTS) {
      DN_STAGE(cur ^ 1, (t + 1) * 64);
      asm volatile("s_waitcnt vmcnt(8)" ::: "memory");
    } else {
      asm volatile("s_waitcnt vmcnt(0)" ::: "memory");
    }
    __builtin_amdgcn_s_barrier();
#pragma unroll
    for (int ks = 0; ks < 2; ++ks) {
      const int k8r = ks * 4 + l16;
      bf16x8 af[8], bb[4];
#pragma unroll
      for (int m = 0; m < 8; ++m) {
        int rw = wm * 128 + m * 16 + lr;
        af[m] = *reinterpret_cast<const bf16x8*>(
            &As[cur][rw * 8 + (k8r ^ (rw & 7))]);
      }
#pragma unroll
      for (int n = 0; n < 4; ++n) {
        int cn = wn * 64 + n * 16 + lr;
        bb[n] = *reinterpret_cast<const bf16x8*>(
            &Bs[cur][cn * 8 + (k8r ^ (cn & 7))]);
      }
#pragma unroll
      for (int m = 0; m < 8; ++m)
#pragma unroll
        for (int n = 0; n < 4; ++n)
          acc[m][n] = mfma16(af[m], bb[n], acc[m][n]);
    }
    __builtin_amdgcn_s_barrier();
    cur ^= 1;
  }
#pragma unroll
  for (int m = 0; m < 8; ++m)
#pragma unroll
    for (int n = 0; n < 4; ++n)
#pragma unroll
      for (int q = 0; q < 4; ++q) {
        int rloc = wm * 128 + m * 16 + l16 * 4 + q;
        int cloc = wn * 64 + n * 16 + lr;
        if (SH) {
          out[(size_t)(row0 + rloc) * HH + (n0 + cloc)] = acc[m][n][q];
        } else if (row0 + rloc < n_rows) {
          eo[(size_t)(base + row0 + rloc) * HH + (n0 + cloc)] = (__bf16)acc[m][n][q];
        }
      }
#undef DN_STAGE
}

// ------------- weighted combine: out += sum_j w_j * eo[row_j] -------------
__global__ __launch_bounds__(256)
void k_combine(const __bf16* __restrict__ eo, const int* __restrict__ row_of,
               const float* __restrict__ wvec, float* __restrict__ out)
{
  const int t = blockIdx.x, tid = threadIdx.x;
  const int h0 = tid * 8;
  float acc[8];
  float4* op = reinterpret_cast<float4*>(out + (size_t)t * HH + h0);
  float4 o0 = op[0], o1 = op[1];
  acc[0] = o0.x; acc[1] = o0.y; acc[2] = o0.z; acc[3] = o0.w;
  acc[4] = o1.x; acc[5] = o1.y; acc[6] = o1.z; acc[7] = o1.w;
#pragma unroll
  for (int j = 0; j < 4; ++j) {
    int r = row_of[t * 4 + j];
    float wj = wvec[t * 4 + j];
    uint4 v = *reinterpret_cast<const uint4*>(eo + (size_t)r * HH + h0);
    unsigned int ws4[4] = {v.x, v.y, v.z, v.w};
#pragma unroll
    for (int q = 0; q < 4; ++q) {
      acc[q * 2 + 0] += wj * bf2f((unsigned short)(ws4[q] & 0xffffu));
      acc[q * 2 + 1] += wj * bf2f((unsigned short)(ws4[q] >> 16));
    }
  }
  o0.x = acc[0]; o0.y = acc[1]; o0.z = acc[2]; o0.w = acc[3];
  o1.x = acc[4]; o1.y = acc[5]; o1.z = acc[6]; o1.w = acc[7];
  op[0] = o0; op[1] = o1;
}

extern "C" void kernel_launch(void* const* d_in, const int* in_sizes, int n_in,
                              void* d_out, int out_size, void* d_ws, size_t ws_size,
                              hipStream_t stream) {
  const float* x  = (const float*)d_in[0];
  const float* gw = (const float*)d_in[1];
  const float* gb = (const float*)d_in[2];
  const float* wg = (const float*)d_in[3];
  const float* wu = (const float*)d_in[4];
  const float* wd = (const float*)d_in[5];
  const float* sg = (const float*)d_in[6];
  const float* su = (const float*)d_in[7];
  const float* sd = (const float*)d_in[8];
  float* out = (float*)d_out;

  char* ws = (char*)d_ws;
  size_t off = 0;
  auto carve = [&](size_t bytes) {
    off = (off + 255) & ~(size_t)255;
    void* p = (void*)(ws + off);
    off += bytes;
    return p;
  };
  int*    topk_idx = (int*)carve((size_t)TT * KK * 4);
  float*  wvec     = (float*)carve((size_t)TT * KK * 4);
  int*    counts   = (int*)carve(EE * 4);
  int*    offs     = (int*)carve(EE * 4);
  int*    list     = (int*)carve((size_t)EE * TT * 4);
  int*    row_of   = (int*)carve((size_t)TT * KK * 4);
  int*    hdr      = (int*)carve(64);
  int*    gu_tab   = (int*)carve(GU_MAXT * 4);
  int*    dn_tab   = (int*)carve(DN_MAXT * 4);
  __bf16* xb       = (__bf16*)carve((size_t)TT * HH * 2);
  __bf16* a_buf    = (__bf16*)carve((size_t)TT * KK * II * 2);
  __bf16* s_buf    = (__bf16*)carve((size_t)TT * IIS * 2);
  __bf16* eo       = (__bf16*)carve((size_t)TT * KK * HH * 2);
  __bf16* wgT = (__bf16*)carve((size_t)EE * II * HH * 2);
  __bf16* wuT = (__bf16*)carve((size_t)EE * II * HH * 2);
  __bf16* wdT = (__bf16*)carve((size_t)EE * HH * II * 2);
  __bf16* sgT = (__bf16*)carve((size_t)IIS * HH * 2);
  __bf16* suT = (__bf16*)carve((size_t)IIS * HH * 2);
  __bf16* sdT = (__bf16*)carve((size_t)HH * IIS * 2);
  const bool big = (off <= ws_size);

  // fused routing + gate/up/shared-gu weight transpose (independent work)
  const int rt_blocks = big ? (TT + TR_GU + TR_SGU) : TT;
  k_route_tr<<<rt_blocks, 256, 0, stream>>>(
      x, gw, gb, topk_idx, wvec, xb, wg, wgT, wu, wuT, sg, sgT, su, suT);
  k_lists<<<1, 1024, 0, stream>>>(topk_idx, counts, offs, list, row_of,
                                  hdr, gu_tab, dn_tab);

  if (big) {
    // fused: gate/up GEMM (counted-vmcnt) + wd/sd transpose trailing blocks
    k_gu_trd<<<GU_MAXT + TRD_BLK, 512, 0, stream>>>(
        xb, wgT, wuT, sgT, suT, counts, offs, list, hdr, gu_tab,
        a_buf, s_buf, wd, wdT, sd, sdT);
    // down GEMM 256x256 (counted-vmcnt; routed -> eo, shared -> out)
    k_down5<<<DN_MAXT, 512, 0, stream>>>(
        a_buf, s_buf, wdT, sdT, counts, offs, hdr, dn_tab, eo, out);
  }
  k_combine<<<TT, 256, 0, stream>>>(eo, row_of, wvec, out);
}